// Round 6
// baseline (284.578 us; speedup 1.0000x reference)
//
#include <hip/hip_runtime.h>
#include <stdint.h>
#include <math.h>

#define NDIM 256
#define BATCH 65536
#define NROT 32640          // 256*255/2

typedef float  f32x4 __attribute__((ext_vector_type(4)));
typedef short  s16x8 __attribute__((ext_vector_type(8)));
typedef unsigned int u32x4 __attribute__((ext_vector_type(4)));
typedef unsigned int u32x2 __attribute__((ext_vector_type(2)));

// round-to-nearest-even float -> bf16 bits
static __device__ __forceinline__ unsigned short f2bf(float f) {
    unsigned int u = __float_as_uint(f);
    u += 0x7fffu + ((u >> 16) & 1u);
    return (unsigned short)(u >> 16);
}
static __device__ __forceinline__ float bf2f(unsigned short h) {
    return __uint_as_float(((unsigned)h) << 16);
}

// split 4 fp32 -> bf16 hi + bf16 lo (packed).  a ~= hi + lo, |err| ~ 2^-18|a|
static __device__ __forceinline__ void split4(f32x4 v, u32x2* hi, u32x2* lo) {
    unsigned short h[4], l[4];
    #pragma unroll
    for (int i = 0; i < 4; i++) {
        h[i] = f2bf(v[i]);
        l[i] = f2bf(v[i] - bf2f(h[i]));
    }
    *hi = (u32x2){ (unsigned)h[0] | ((unsigned)h[1] << 16),
                   (unsigned)h[2] | ((unsigned)h[3] << 16) };
    *lo = (u32x2){ (unsigned)l[0] | ((unsigned)l[1] << 16),
                   (unsigned)l[2] | ((unsigned)l[3] << 16) };
}
static __device__ __forceinline__ void split8(const float* v, u32x4* hi, u32x4* lo) {
    unsigned short h[8], l[8];
    #pragma unroll
    for (int i = 0; i < 8; i++) {
        h[i] = f2bf(v[i]);
        l[i] = f2bf(v[i] - bf2f(h[i]));
    }
    *hi = (u32x4){ (unsigned)h[0] | ((unsigned)h[1] << 16),
                   (unsigned)h[2] | ((unsigned)h[3] << 16),
                   (unsigned)h[4] | ((unsigned)h[5] << 16),
                   (unsigned)h[6] | ((unsigned)h[7] << 16) };
    *lo = (u32x4){ (unsigned)l[0] | ((unsigned)l[1] << 16),
                   (unsigned)l[2] | ((unsigned)l[3] << 16),
                   (unsigned)l[4] | ((unsigned)l[5] << 16),
                   (unsigned)l[6] | ((unsigned)l[7] << 16) };
}

// nearest 4-aligned sweep boundary to k*(NROT/pblk); shared by k_blocks
// and k_combine (the block-diagonal skip logic depends on agreement).
static __device__ __forceinline__ int sweep_bound(int k, int pblk) {
    int target = k * (NROT / pblk);
    int best = 0, bd = 0x7fffffff;
    for (int i = 0; i <= 256; i += 4) {
        int pre = i * 255 - (i * (i - 1)) / 2;
        int d = pre - target; d = (d < 0) ? -d : d;
        if (d < bd) { bd = d; best = i; }
    }
    return best;
}

// ---------------- kernel 0: angle table (cos,sin) for both rot sets ---------
__global__ __launch_bounds__(256) void k_cs(const float* __restrict__ r1,
                                            const float* __restrict__ r2,
                                            float2* __restrict__ cs) {
    int i = blockIdx.x * 256 + threadIdx.x;          // 0 .. 2*NROT-1
    float th = (i < NROT) ? r1[i] : r2[i - NROT];
    float sv, cv; sincosf(th, &sv, &cv);
    cs[i] = make_float2(cv, sv);
}

// ---------------- kernel 1: build pblk partial Givens products per matrix ---
// Structural occupancy fix (R5 post-mortem): pblk=64 halves the worst-WG
// serial chain (4-aligned sweep floor: earliest block = sweeps 0-3, one
// 252-iter fused j-loop) and gives 512 WGs; LDS cut to 76.9 KB (csb single
// buffer -- the R3 double-buffer was within noise) so 2 WGs/CU fit and all
// 512 run concurrently on separate SIMDs.
__global__ __launch_bounds__(64) void k_blocks(const float2* __restrict__ cs,
                                               float* __restrict__ bmats, int pblk) {
    __shared__ float colb[264 * 64];
    __shared__ float2 csb[256 * 4];     // single-buffered steady angles
    __shared__ float2 tri[24 * 6];      // all groups' triangle angles

    const int t = threadIdx.x;          // column within chunk
    const int bid = blockIdx.x;
    const int chunk = bid & 3;          // 0..3 (64 cols each)
    const int b = (bid >> 2) % pblk;    // 0..pblk-1
    const int set = (bid >> 2) / pblk;  // 0 = rots1, 1 = rots2
    const int col0 = chunk * 64;
    const float2* cst = cs + (size_t)set * NROT;

    const int s0 = sweep_bound(b, pblk);
    const int s1 = sweep_bound(b + 1, pblk);
    const int ngroups = (s1 - s0) >> 2;

    // zero colb (incl. pad rows 256..263), set identity diagonal
    {
        const f32x4 z = {0.f, 0.f, 0.f, 0.f};
        #pragma unroll 11
        for (int q = 0; q < 66; q++)
            *(f32x4*)&colb[(q * 64 + t) * 4] = z;
        colb[(col0 + t) * 64 + t] = 1.0f;
    }

    // stage all triangle angles (6 per group) into LDS
    for (int k = t; k < ngroups * 6; k += 64) {
        int g = k / 6, q = k - g * 6;
        int a  = (q < 3) ? 0 : ((q < 5) ? 1 : 2);
        int bb = (q < 3) ? (q + 1) : ((q < 5) ? (q - 1) : 3);
        int m0 = s0 + g * 4;
        int m = m0 + a;
        int base = m * 255 - (m * (m - 1)) / 2;
        tri[k] = cst[base - m - 1 + m0 + bb];
    }
    // single-wave WG: DS pipe is in-order per wave, no barrier needed

    float2 gv[16];                      // in-flight staging registers
    {
        const int m0g = s0;
        int offg[4];
        #pragma unroll
        for (int a = 0; a < 4; a++) {
            int m = m0g + a;
            offg[a] = m * 255 - (m * (m - 1)) / 2 - m - 1;
        }
        #pragma unroll
        for (int it = 0; it < 16; it++) {
            int k = t + it * 64;
            int jj = k >> 2, a = k & 3;
            int j = m0g + 4 + jj;
            gv[it] = (j < 256) ? cst[offg[a] + j] : make_float2(1.f, 0.f);
        }
        #pragma unroll
        for (int it = 0; it < 16; it++)
            csb[t + it * 64] = gv[it];
    }

    for (int g = 0; g < ngroups; g++) {
        const int m0 = s0 + g * 4;
        const int n_j = 252 - m0;
        const int n_p = (n_j > 0) ? ((n_j + 7) & ~7) : 0;
        const float* csbuf = (const float*)&csb[0];

        // issue NEXT group's staging loads (latency hides under this j-loop;
        // commit to csb happens after the j-loop's reads -- in-order DS pipe)
        const bool have_next = (g + 1 < ngroups);
        if (have_next) {
            const int m0g = m0 + 4;
            int offg[4];
            #pragma unroll
            for (int a = 0; a < 4; a++) {
                int m = m0g + a;
                offg[a] = m * 255 - (m * (m - 1)) / 2 - m - 1;
            }
            #pragma unroll
            for (int it = 0; it < 16; it++) {
                int k = t + it * 64;
                int jj = k >> 2, a = k & 3;
                int j = m0g + 4 + jj;
                gv[it] = (j < 256) ? cst[offg[a] + j] : make_float2(1.f, 0.f);
            }
        }

        float u0 = colb[(m0 + 0) * 64 + t];
        float u1 = colb[(m0 + 1) * 64 + t];
        float u2 = colb[(m0 + 2) * 64 + t];
        float u3 = colb[(m0 + 3) * 64 + t];

        {
            float2 cv; float nr;
            cv = tri[g * 6 + 0]; nr = cv.y * u0 + cv.x * u1; u0 = cv.x * u0 - cv.y * u1; u1 = nr;
            cv = tri[g * 6 + 1]; nr = cv.y * u0 + cv.x * u2; u0 = cv.x * u0 - cv.y * u2; u2 = nr;
            cv = tri[g * 6 + 2]; nr = cv.y * u0 + cv.x * u3; u0 = cv.x * u0 - cv.y * u3; u3 = nr;
            cv = tri[g * 6 + 3]; nr = cv.y * u1 + cv.x * u2; u1 = cv.x * u1 - cv.y * u2; u2 = nr;
            cv = tri[g * 6 + 4]; nr = cv.y * u1 + cv.x * u3; u1 = cv.x * u1 - cv.y * u3; u3 = nr;
            cv = tri[g * 6 + 5]; nr = cv.y * u2 + cv.x * u3; u2 = cv.x * u2 - cv.y * u3; u3 = nr;
        }

        if (n_p > 0) {
            float rbuf[8];
            f32x4 abuf[8][2];
            #pragma unroll
            for (int p = 0; p < 8; p++) {
                rbuf[p] = colb[(m0 + 4 + p) * 64 + t];
                abuf[p][0] = *(const f32x4*)&csbuf[p * 8 + 0];
                abuf[p][1] = *(const f32x4*)&csbuf[p * 8 + 4];
            }
            for (int c = 0; c < n_p; c += 8) {
                #pragma unroll
                for (int p = 0; p < 8; p++) {
                    const int j = m0 + 4 + c + p;
                    float r = rbuf[p];
                    f32x4 A01 = abuf[p][0], A23 = abuf[p][1];
                    int jn = j + 8; jn = (jn < 263) ? jn : 263;
                    int cn = c + p + 8; cn = (cn < n_p) ? cn : (n_p - 1);
                    rbuf[p] = colb[jn * 64 + t];
                    abuf[p][0] = *(const f32x4*)&csbuf[cn * 8 + 0];
                    abuf[p][1] = *(const f32x4*)&csbuf[cn * 8 + 4];
                    float nr;
                    nr = A01[1] * u0 + A01[0] * r; u0 = A01[0] * u0 - A01[1] * r; r = nr;
                    nr = A01[3] * u1 + A01[2] * r; u1 = A01[2] * u1 - A01[3] * r; r = nr;
                    nr = A23[1] * u2 + A23[0] * r; u2 = A23[0] * u2 - A23[1] * r; r = nr;
                    nr = A23[3] * u3 + A23[2] * r; u3 = A23[2] * u3 - A23[3] * r; r = nr;
                    colb[j * 64 + t] = r;
                }
            }
        }
        colb[(m0 + 0) * 64 + t] = u0;
        colb[(m0 + 1) * 64 + t] = u1;
        colb[(m0 + 2) * 64 + t] = u2;
        colb[(m0 + 3) * 64 + t] = u3;

        // commit next group's staged angles (after this group's csb reads)
        if (have_next) {
            #pragma unroll
            for (int it = 0; it < 16; it++)
                csb[t + it * 64] = gv[it];
        }
    }

    float* outm = bmats + (size_t)(set * pblk + b) * 65536;
    for (int r = 0; r < 256; r++)
        outm[(size_t)r * 256 + col0 + t] = colb[r * 64 + t];
}

// ---------------- x row-normalize -> bf16, 64 rows per item -----------------
static __device__ __forceinline__ void xnorm_item(const float* __restrict__ xg,
                                                  unsigned short* __restrict__ xbf,
                                                  int id, int tid) {
    const int w = tid >> 6, lane = tid & 63;
    const int r0 = id * 64;
    #pragma unroll 2
    for (int p = 0; p < 16; p++) {
        int row = r0 + p * 4 + w;
        f32x4 v = *(const f32x4*)&xg[(size_t)row * 256 + lane * 4];
        float s = v[0] * v[0] + v[1] * v[1] + v[2] * v[2] + v[3] * v[3];
        #pragma unroll
        for (int off = 32; off; off >>= 1) s += __shfl_xor(s, off, 64);
        float sc = 1.0f / sqrtf(s);
        unsigned short h0 = f2bf(v[0] * sc), h1 = f2bf(v[1] * sc);
        unsigned short h2 = f2bf(v[2] * sc), h3 = f2bf(v[3] * sc);
        u32x2 pk = { (unsigned)h0 | ((unsigned)h1 << 16),
                     (unsigned)h2 | ((unsigned)h3 << 16) };
        *(u32x2*)&xbf[(size_t)row * 256 + lane * 4] = pk;
    }
}

// ---------------- pipelined 64x64 matmul tile helpers -----------------------
// LDS layout: Ahi/Alo/Bhi/Blo each [2][64*40] (double-buffered, 40 KB total).
#define TB 2560   // 64*40 shorts per buffer

static __device__ __forceinline__ void tile_issueA(const float* __restrict__ Am,
                                                   int tr, int kb, int tid,
                                                   f32x4 va[2]) {
    #pragma unroll
    for (int it = 0; it < 2; it++) {
        int flat = tid + it * 256;
        int r = flat >> 3, c4 = flat & 7;
        va[it] = *(const f32x4*)&Am[(size_t)(tr * 64 + r) * 256 + kb * 32 + c4 * 4];
    }
}
static __device__ __forceinline__ void tile_issueB(const float* __restrict__ Bm,
                                                   int tc, int kb, int bn, int bkq,
                                                   float vb[8]) {
    #pragma unroll
    for (int i = 0; i < 8; i++)
        vb[i] = Bm[(size_t)(kb * 32 + bkq * 8 + i) * 256 + tc * 64 + bn];
}
static __device__ __forceinline__ void tile_commit(unsigned short* __restrict__ Ahi,
                                                   unsigned short* __restrict__ Alo,
                                                   unsigned short* __restrict__ Bhi,
                                                   unsigned short* __restrict__ Blo,
                                                   int tid, int bn, int bkq,
                                                   const f32x4 va[2], const float vb[8]) {
    #pragma unroll
    for (int it = 0; it < 2; it++) {
        int flat = tid + it * 256;
        int r = flat >> 3, c4 = flat & 7;
        u32x2 hi, lo; split4(va[it], &hi, &lo);
        *(u32x2*)&Ahi[r * 40 + c4 * 4] = hi;
        *(u32x2*)&Alo[r * 40 + c4 * 4] = lo;
    }
    u32x4 hi8, lo8; split8(vb, &hi8, &lo8);
    *(u32x4*)&Bhi[bn * 40 + bkq * 8] = hi8;
    *(u32x4*)&Blo[bn * 40 + bkq * 8] = lo8;
}
static __device__ __forceinline__ void tile_mfma(const unsigned short* __restrict__ Ahi,
                                                 const unsigned short* __restrict__ Alo,
                                                 const unsigned short* __restrict__ Bhi,
                                                 const unsigned short* __restrict__ Blo,
                                                 int mh, int nh, int l15, int lq,
                                                 f32x4 acc[2][2]) {
    s16x8 ah[2], al[2], bh[2], bl[2];
    #pragma unroll
    for (int tm = 0; tm < 2; tm++) {
        ah[tm] = *(const s16x8*)&Ahi[(mh + tm * 16 + l15) * 40 + lq * 8];
        al[tm] = *(const s16x8*)&Alo[(mh + tm * 16 + l15) * 40 + lq * 8];
    }
    #pragma unroll
    for (int tn = 0; tn < 2; tn++) {
        bh[tn] = *(const s16x8*)&Bhi[(nh + tn * 16 + l15) * 40 + lq * 8];
        bl[tn] = *(const s16x8*)&Blo[(nh + tn * 16 + l15) * 40 + lq * 8];
    }
    #pragma unroll
    for (int tm = 0; tm < 2; tm++)
        #pragma unroll
        for (int tn = 0; tn < 2; tn++) {
            acc[tm][tn] = __builtin_amdgcn_mfma_f32_16x16x32_bf16(ah[tm], bh[tn], acc[tm][tn], 0, 0, 0);
            acc[tm][tn] = __builtin_amdgcn_mfma_f32_16x16x32_bf16(ah[tm], bl[tn], acc[tm][tn], 0, 0, 0);
            acc[tm][tn] = __builtin_amdgcn_mfma_f32_16x16x32_bf16(al[tm], bh[tn], acc[tm][tn], 0, 0, 0);
        }
}

// one 64x64 combine tile: dst[p] = src[2p+1] @ src[2p], software-pipelined:
// 2-deep register prefetch of global loads + double-buffered LDS, one
// __syncthreads per k-phase -> HBM/L2 latency hidden.
static __device__ void combine_tile(const float* __restrict__ src,
                                    float* __restrict__ dst,
                                    int half, int pblk, int bx, int by, int tid,
                                    unsigned short* Ahi, unsigned short* Alo,
                                    unsigned short* Bhi, unsigned short* Blo) {
    const int set = by / half, pidx = by % half;
    const int stride = pblk / (2 * half);
    const int s0A = sweep_bound((2 * pidx + 1) * stride, pblk);
    const float* Am = src + (size_t)(set * 2 * half + 2 * pidx + 1) * 65536;
    const float* Bm = src + (size_t)(set * 2 * half + 2 * pidx) * 65536;
    float* Dm = dst + (size_t)(set * half + pidx) * 65536;
    const int tr = bx >> 2, tc = bx & 3;

    if (tr * 64 + 64 <= s0A) {                 // pure copy tile: D = B
        #pragma unroll
        for (int it = 0; it < 4; it++) {
            int flat = tid + it * 256;
            int r = flat >> 4, c4 = flat & 15;
            size_t idx = (size_t)(tr * 64 + r) * 256 + tc * 64 + c4 * 4;
            *(f32x4*)&Dm[idx] = *(const f32x4*)&Bm[idx];
        }
        return;
    }
    const int kb0 = (tr * 64 >= s0A) ? (s0A >> 5) : 0;

    const int lane = tid & 63, w = tid >> 6;
    const int mh = (w >> 1) * 32, nh = (w & 1) * 32;
    const int l15 = lane & 15, lq = lane >> 4;
    const int bn = tid & 63, bkq = tid >> 6;

    f32x4 acc[2][2];
    #pragma unroll
    for (int i = 0; i < 2; i++)
        #pragma unroll
        for (int j = 0; j < 2; j++) acc[i][j] = (f32x4){0.f, 0.f, 0.f, 0.f};

    f32x4 vaE[2], vaO[2]; float vbE[8], vbO[8];
    tile_issueA(Am, tr, kb0, tid, vaE);
    tile_issueB(Bm, tc, kb0, bn, bkq, vbE);
    if (kb0 + 1 < 8) {
        tile_issueA(Am, tr, kb0 + 1, tid, vaO);
        tile_issueB(Bm, tc, kb0 + 1, bn, bkq, vbO);
    }
    tile_commit(Ahi, Alo, Bhi, Blo, tid, bn, bkq, vaE, vbE);
    __syncthreads();

    for (int kb = kb0; kb < 8; kb++) {
        const int cur = (kb - kb0) & 1;
        if (cur == 0) {
            if (kb + 2 < 8) {
                tile_issueA(Am, tr, kb + 2, tid, vaE);
                tile_issueB(Bm, tc, kb + 2, bn, bkq, vbE);
            }
            if (kb + 1 < 8)
                tile_commit(Ahi + TB, Alo + TB, Bhi + TB, Blo + TB,
                            tid, bn, bkq, vaO, vbO);
            tile_mfma(Ahi, Alo, Bhi, Blo, mh, nh, l15, lq, acc);
        } else {
            if (kb + 2 < 8) {
                tile_issueA(Am, tr, kb + 2, tid, vaO);
                tile_issueB(Bm, tc, kb + 2, bn, bkq, vbO);
            }
            if (kb + 1 < 8)
                tile_commit(Ahi, Alo, Bhi, Blo, tid, bn, bkq, vaE, vbE);
            tile_mfma(Ahi + TB, Alo + TB, Bhi + TB, Blo + TB, mh, nh, l15, lq, acc);
        }
        __syncthreads();
    }
    #pragma unroll
    for (int tm = 0; tm < 2; tm++)
        #pragma unroll
        for (int tn = 0; tn < 2; tn++)
            #pragma unroll
            for (int r = 0; r < 4; r++)
                Dm[(size_t)(tr * 64 + mh + tm * 16 + lq * 4 + r) * 256
                   + tc * 64 + nh + tn * 16 + l15] = acc[tm][tn][r];
}

// one 64x64 tile of AT/BT = M2 @ diag(cos|sin(phases)) @ M1 -> bf16
static __device__ void abt_tile(const float* __restrict__ mats,
                                const float* __restrict__ phases,
                                unsigned short* __restrict__ abtp,
                                int bx, int v, int tid,
                                unsigned short* Ahi, unsigned short* Alo,
                                unsigned short* Bhi, unsigned short* Blo) {
    const float* Am = mats + 65536;    // M2
    const float* Bm = mats;            // M1
    const int tr = bx >> 2, tc = bx & 3;

    const int lane = tid & 63, w = tid >> 6;
    const int mh = (w >> 1) * 32, nh = (w & 1) * 32;
    const int l15 = lane & 15, lq = lane >> 4;
    const int bn = tid & 63, bkq = tid >> 6;

    f32x4 acc[2][2];
    #pragma unroll
    for (int i = 0; i < 2; i++)
        #pragma unroll
        for (int j = 0; j < 2; j++) acc[i][j] = (f32x4){0.f, 0.f, 0.f, 0.f};

    auto issueBs = [&](int kb, float vb[8]) {
        #pragma unroll
        for (int i = 0; i < 8; i++) {
            int kg = kb * 32 + bkq * 8 + i;          // wave-uniform k index
            float ph = phases[kg];
            float sc = v ? sinf(ph) : cosf(ph);
            vb[i] = Bm[(size_t)kg * 256 + tc * 64 + bn] * sc;
        }
    };

    f32x4 vaE[2], vaO[2]; float vbE[8], vbO[8];
    tile_issueA(Am, tr, 0, tid, vaE); issueBs(0, vbE);
    tile_issueA(Am, tr, 1, tid, vaO); issueBs(1, vbO);
    tile_commit(Ahi, Alo, Bhi, Blo, tid, bn, bkq, vaE, vbE);
    __syncthreads();

    for (int kb = 0; kb < 8; kb++) {
        const int cur = kb & 1;
        if (cur == 0) {
            if (kb + 2 < 8) { tile_issueA(Am, tr, kb + 2, tid, vaE); issueBs(kb + 2, vbE); }
            if (kb + 1 < 8)
                tile_commit(Ahi + TB, Alo + TB, Bhi + TB, Blo + TB,
                            tid, bn, bkq, vaO, vbO);
            tile_mfma(Ahi, Alo, Bhi, Blo, mh, nh, l15, lq, acc);
        } else {
            if (kb + 2 < 8) { tile_issueA(Am, tr, kb + 2, tid, vaO); issueBs(kb + 2, vbO); }
            if (kb + 1 < 8)
                tile_commit(Ahi, Alo, Bhi, Blo, tid, bn, bkq, vaE, vbE);
            tile_mfma(Ahi + TB, Alo + TB, Bhi + TB, Blo + TB, mh, nh, l15, lq, acc);
        }
        __syncthreads();
    }
    #pragma unroll
    for (int tm = 0; tm < 2; tm++)
        #pragma unroll
        for (int tn = 0; tn < 2; tn++)
            #pragma unroll
            for (int r = 0; r < 4; r++)
                abtp[(size_t)(v * 256 + tr * 64 + mh + tm * 16 + lq * 4 + r) * 256
                     + tc * 64 + nh + tn * 16 + l15] = f2bf(acc[tm][tn][r]);
}

// ---------------- kernel wrappers -------------------------------------------
__global__ __launch_bounds__(256) void k_combine(const float* __restrict__ src,
                                                 float* __restrict__ dst,
                                                 int half, int pblk,
                                                 const float* __restrict__ xg,
                                                 unsigned short* __restrict__ xbf) {
    __shared__ unsigned short Ahi[2 * TB], Alo[2 * TB], Bhi[2 * TB], Blo[2 * TB];
    const int by = blockIdx.y, tid = threadIdx.x;
    if (by >= 2 * half) {
        xnorm_item(xg, xbf, (by - 2 * half) * 16 + blockIdx.x, tid);
        return;
    }
    combine_tile(src, dst, half, pblk, blockIdx.x, by, tid, Ahi, Alo, Bhi, Blo);
}

__global__ __launch_bounds__(256) void k_abt(const float* __restrict__ mats,
                                             const float* __restrict__ phases,
                                             unsigned short* __restrict__ abtp) {
    __shared__ unsigned short Ahi[2 * TB], Alo[2 * TB], Bhi[2 * TB], Blo[2 * TB];
    abt_tile(mats, phases, abtp, blockIdx.x, blockIdx.y, threadIdx.x,
             Ahi, Alo, Bhi, Blo);
}

// ---------------- kernel 4b: per-row 1/||x|| (fallback path) ----------------
__global__ __launch_bounds__(256) void k_norm(const float* __restrict__ x,
                                              float* __restrict__ invn) {
    const int row = blockIdx.x * 4 + (threadIdx.x >> 6);
    const int lane = threadIdx.x & 63;
    f32x4 v = *(const f32x4*)&x[(size_t)row * 256 + lane * 4];
    float s = v[0] * v[0] + v[1] * v[1] + v[2] * v[2] + v[3] * v[3];
    for (int off = 32; off; off >>= 1) s += __shfl_xor(s, off, 64);
    if (lane == 0) invn[row] = 1.0f / sqrtf(s);
}

// ---------------- kernel 5a: GEMM + |.|^2 from pre-converted bf16 x ---------
// XCD swizzle: remap l=(y*4+x) -> L=(l&7)*256+(l>>3): each XCD gets 64
// contiguous rb x all 4 cb -> x-tile fetched once per XCD (4 MB = L2-sized).
#define BKP 136   // padded LDS k-stride (bf16 elems)
__global__ __launch_bounds__(256) void k_gemm_bf(const unsigned short* __restrict__ xbf,
                                                 const unsigned short* __restrict__ abt,
                                                 float* __restrict__ out) {
    __shared__ unsigned short As[128 * BKP];
    __shared__ unsigned short Bs[128 * BKP];
    const int tid = threadIdx.x;
    const int l  = blockIdx.y * 4 + blockIdx.x;
    const int L  = (l & 7) * 256 + (l >> 3);
    const int cb = L & 3;               // 0..3  (64 out-cols each)
    const int rb = L >> 2;              // 0..511
    const int lane = tid & 63, w = tid >> 6;

    f32x4 acc[16];
    #pragma unroll
    for (int i = 0; i < 16; i++) acc[i] = (f32x4){0.f, 0.f, 0.f, 0.f};

    int rA[8], cA[8], grB[8];
    #pragma unroll
    for (int it = 0; it < 8; it++) {
        int flat = tid + it * 256;
        rA[it] = flat >> 4; cA[it] = flat & 15;
        int r = rA[it];
        grB[it] = (r < 64) ? (cb * 64 + r) : (256 + cb * 64 + (r - 64));
    }

    u32x4 pa[8], pb[8];
    #pragma unroll
    for (int it = 0; it < 8; it++) {
        pa[it] = *(const u32x4*)&xbf[(size_t)(rb * 128 + rA[it]) * 256 + cA[it] * 8];
        pb[it] = *(const u32x4*)&abt[(size_t)grB[it] * 256 + cA[it] * 8];
    }
    #pragma unroll
    for (int it = 0; it < 8; it++) {
        *(u32x4*)&As[rA[it] * BKP + cA[it] * 8] = pa[it];
        *(u32x4*)&Bs[rA[it] * BKP + cA[it] * 8] = pb[it];
    }
    __syncthreads();
    #pragma unroll
    for (int it = 0; it < 8; it++) {
        pa[it] = *(const u32x4*)&xbf[(size_t)(rb * 128 + rA[it]) * 256 + 128 + cA[it] * 8];
        pb[it] = *(const u32x4*)&abt[(size_t)grB[it] * 256 + 128 + cA[it] * 8];
    }

    auto compute = [&]() {
        #pragma unroll
        for (int ks = 0; ks < 4; ks++) {
            const int k0 = ks * 32 + (lane >> 4) * 8;
            s16x8 a[2], b[8];
            #pragma unroll
            for (int tm = 0; tm < 2; tm++)
                a[tm] = *(const s16x8*)&As[(w * 32 + tm * 16 + (lane & 15)) * BKP + k0];
            #pragma unroll
            for (int tn = 0; tn < 8; tn++)
                b[tn] = *(const s16x8*)&Bs[(tn * 16 + (lane & 15)) * BKP + k0];
            #pragma unroll
            for (int tm = 0; tm < 2; tm++)
                #pragma unroll
                for (int tn = 0; tn < 8; tn++)
                    acc[tm * 8 + tn] = __builtin_amdgcn_mfma_f32_16x16x32_bf16(
                        a[tm], b[tn], acc[tm * 8 + tn], 0, 0, 0);
        }
    };
    compute();                 // kb=0
    __syncthreads();
    #pragma unroll
    for (int it = 0; it < 8; it++) {
        *(u32x4*)&As[rA[it] * BKP + cA[it] * 8] = pa[it];
        *(u32x4*)&Bs[rA[it] * BKP + cA[it] * 8] = pb[it];
    }
    __syncthreads();
    compute();                 // kb=1

    const int qr = lane >> 4, c = lane & 15;
    #pragma unroll
    for (int tm = 0; tm < 2; tm++) {
        #pragma unroll
        for (int tn = 0; tn < 4; tn++) {
            f32x4 p = acc[tm * 8 + tn];
            f32x4 q = acc[tm * 8 + tn + 4];
            #pragma unroll
            for (int r = 0; r < 4; r++) {
                int m = w * 32 + tm * 16 + qr * 4 + r;
                out[(size_t)(rb * 128 + m) * 256 + cb * 64 + tn * 16 + c] =
                    p[r] * p[r] + q[r] * q[r];
            }
        }
    }
}

// ---------------- kernel 5b: GEMM + |.|^2 from fp32 x (fallback) ------------
__global__ __launch_bounds__(256) void k_gemm_f32(const float* __restrict__ x,
                                                  const unsigned short* __restrict__ abt,
                                                  const float* __restrict__ invn,
                                                  float* __restrict__ out) {
    __shared__ unsigned short As[128 * BKP];
    __shared__ unsigned short Bs[128 * BKP];
    const int tid = threadIdx.x;
    const int l  = blockIdx.y * 4 + blockIdx.x;
    const int L  = (l & 7) * 256 + (l >> 3);
    const int cb = L & 3;
    const int rb = L >> 2;
    const int lane = tid & 63, w = tid >> 6;

    f32x4 acc[16];
    #pragma unroll
    for (int i = 0; i < 16; i++) acc[i] = (f32x4){0.f, 0.f, 0.f, 0.f};

    for (int kb = 0; kb < 2; kb++) {
        __syncthreads();
        #pragma unroll
        for (int it = 0; it < 16; it++) {
            int flat = tid + it * 256;
            int r = flat >> 5, c4 = flat & 31;
            f32x4 v = *(const f32x4*)&x[(size_t)(rb * 128 + r) * 256 + kb * 128 + c4 * 4];
            float sc = invn[rb * 128 + r];
            v[0] *= sc; v[1] *= sc; v[2] *= sc; v[3] *= sc;
            unsigned short h0 = f2bf(v[0]), h1 = f2bf(v[1]);
            unsigned short h2 = f2bf(v[2]), h3 = f2bf(v[3]);
            u32x2 pk = { (unsigned)h0 | ((unsigned)h1 << 16),
                         (unsigned)h2 | ((unsigned)h3 << 16) };
            *(u32x2*)&As[r * BKP + c4 * 4] = pk;
        }
        #pragma unroll
        for (int it = 0; it < 8; it++) {
            int flat = tid + it * 256;
            int r = flat >> 4, c8 = flat & 15;
            int gr = (r < 64) ? (cb * 64 + r) : (256 + cb * 64 + (r - 64));
            u32x4 vv = *(const u32x4*)&abt[(size_t)gr * 256 + kb * 128 + c8 * 8];
            *(u32x4*)&Bs[r * BKP + c8 * 8] = vv;
        }
        __syncthreads();
        #pragma unroll
        for (int ks = 0; ks < 4; ks++) {
            const int k0 = ks * 32 + (lane >> 4) * 8;
            s16x8 a[2], b[8];
            #pragma unroll
            for (int tm = 0; tm < 2; tm++)
                a[tm] = *(const s16x8*)&As[(w * 32 + tm * 16 + (lane & 15)) * BKP + k0];
            #pragma unroll
            for (int tn = 0; tn < 8; tn++)
                b[tn] = *(const s16x8*)&Bs[(tn * 16 + (lane & 15)) * BKP + k0];
            #pragma unroll
            for (int tm = 0; tm < 2; tm++)
                #pragma unroll
                for (int tn = 0; tn < 8; tn++)
                    acc[tm * 8 + tn] = __builtin_amdgcn_mfma_f32_16x16x32_bf16(
                        a[tm], b[tn], acc[tm * 8 + tn], 0, 0, 0);
        }
    }

    const int qr = lane >> 4, c = lane & 15;
    #pragma unroll
    for (int tm = 0; tm < 2; tm++) {
        #pragma unroll
        for (int tn = 0; tn < 4; tn++) {
            f32x4 p = acc[tm * 8 + tn];
            f32x4 q = acc[tm * 8 + tn + 4];
            #pragma unroll
            for (int r = 0; r < 4; r++) {
                int m = w * 32 + tm * 16 + qr * 4 + r;
                out[(size_t)(rb * 128 + m) * 256 + cb * 64 + tn * 16 + c] =
                    p[r] * p[r] + q[r] * q[r];
            }
        }
    }
}

// ---------------- host ------------------------------------------------------
extern "C" void kernel_launch(void* const* d_in, const int* in_sizes, int n_in,
                              void* d_out, int out_size, void* d_ws, size_t ws_size,
                              hipStream_t stream) {
    (void)in_sizes; (void)n_in; (void)out_size;
    const float* x      = (const float*)d_in[0];
    const float* rots1  = (const float*)d_in[1];
    const float* phases = (const float*)d_in[2];
    const float* rots2  = (const float*)d_in[3];
    float* out = (float*)d_out;
    char* ws = (char*)d_ws;

    const size_t MAT = 262144;                 // 256x256 fp32
    // pblk=64 halves the k_blocks critical path (4-aligned sweep floor) and
    // fills 2 WGs/CU; falls back to 32/16 if the workspace is too small.
    int pblk = 64;
    while (pblk > 16 &&
           (size_t)3 * pblk * MAT + 2 * MAT + (size_t)BATCH * 512 > ws_size)
        pblk >>= 1;
    const size_t offA   = 0;
    const size_t offB   = offA + (size_t)2 * pblk * MAT;   // A: 2*pblk mats
    const size_t offABT = offB + (size_t)pblk * MAT;       // B: pblk mats
    const size_t offINV = offABT + MAT;
    const size_t offXBF = offINV + MAT;
    const bool use_xbf = (offXBF + (size_t)BATCH * 512) <= ws_size;

    float*          A    = (float*)(ws + offA);
    float*          B    = (float*)(ws + offB);
    unsigned short* abt  = (unsigned short*)(ws + offABT);
    float*          invn = (float*)(ws + offINV);
    unsigned short* xbf  = (unsigned short*)(ws + offXBF);
    // cos/sin table overlays the B ping-pong buffer: written by k_cs, read by
    // k_blocks, dead by the time combine round 1 overwrites B.
    float2*         cs   = (float2*)(ws + offB);

    k_cs<<<(2 * NROT) / 256, 256, 0, stream>>>(rots1, rots2, cs);
    k_blocks<<<8 * pblk, 64, 0, stream>>>(cs, A, pblk);

    float* srcp = A; float* dstp = B;
    bool first = true;
    for (int half = pblk / 2; half >= 1; half >>= 1) {
        const int xny = (first && use_xbf) ? 64 : 0;
        k_combine<<<dim3(16, 2 * half + xny), 256, 0, stream>>>(srcp, dstp, half,
                                                                pblk, x, xbf);
        float* tmp = srcp; srcp = dstp; dstp = tmp;
        first = false;
    }
    k_abt<<<dim3(16, 2), 256, 0, stream>>>(srcp, phases, abt);

    if (use_xbf) {
        k_gemm_bf<<<dim3(4, BATCH / 128), 256, 0, stream>>>(xbf, abt, out);
    } else {
        k_norm<<<BATCH / 4, 256, 0, stream>>>(x, invn);
        k_gemm_f32<<<dim3(4, BATCH / 128), 256, 0, stream>>>(x, abt, invn, out);
    }
}

// Round 7
// 279.826 us; speedup vs baseline: 1.0170x; 1.0170x over previous
//
#include <hip/hip_runtime.h>
#include <stdint.h>
#include <math.h>

#define NDIM 256
#define BATCH 65536
#define NROT 32640          // 256*255/2

typedef float  f32x4 __attribute__((ext_vector_type(4)));
typedef short  s16x8 __attribute__((ext_vector_type(8)));
typedef unsigned int u32x4 __attribute__((ext_vector_type(4)));
typedef unsigned int u32x2 __attribute__((ext_vector_type(2)));

// round-to-nearest-even float -> bf16 bits
static __device__ __forceinline__ unsigned short f2bf(float f) {
    unsigned int u = __float_as_uint(f);
    u += 0x7fffu + ((u >> 16) & 1u);
    return (unsigned short)(u >> 16);
}
static __device__ __forceinline__ float bf2f(unsigned short h) {
    return __uint_as_float(((unsigned)h) << 16);
}

// split 4 fp32 -> bf16 hi + bf16 lo (packed).  a ~= hi + lo, |err| ~ 2^-18|a|
static __device__ __forceinline__ void split4(f32x4 v, u32x2* hi, u32x2* lo) {
    unsigned short h[4], l[4];
    #pragma unroll
    for (int i = 0; i < 4; i++) {
        h[i] = f2bf(v[i]);
        l[i] = f2bf(v[i] - bf2f(h[i]));
    }
    *hi = (u32x2){ (unsigned)h[0] | ((unsigned)h[1] << 16),
                   (unsigned)h[2] | ((unsigned)h[3] << 16) };
    *lo = (u32x2){ (unsigned)l[0] | ((unsigned)l[1] << 16),
                   (unsigned)l[2] | ((unsigned)l[3] << 16) };
}
static __device__ __forceinline__ void split8(const float* v, u32x4* hi, u32x4* lo) {
    unsigned short h[8], l[8];
    #pragma unroll
    for (int i = 0; i < 8; i++) {
        h[i] = f2bf(v[i]);
        l[i] = f2bf(v[i] - bf2f(h[i]));
    }
    *hi = (u32x4){ (unsigned)h[0] | ((unsigned)h[1] << 16),
                   (unsigned)h[2] | ((unsigned)h[3] << 16),
                   (unsigned)h[4] | ((unsigned)h[5] << 16),
                   (unsigned)h[6] | ((unsigned)h[7] << 16) };
    *lo = (u32x4){ (unsigned)l[0] | ((unsigned)l[1] << 16),
                   (unsigned)l[2] | ((unsigned)l[3] << 16),
                   (unsigned)l[4] | ((unsigned)l[5] << 16),
                   (unsigned)l[6] | ((unsigned)l[7] << 16) };
}

// nearest 4-aligned sweep boundary to k*(NROT/pblk); shared by k_blocks
// and k_combine (the block-diagonal skip logic depends on agreement).
static __device__ __forceinline__ int sweep_bound(int k, int pblk) {
    int target = k * (NROT / pblk);
    int best = 0, bd = 0x7fffffff;
    for (int i = 0; i <= 256; i += 4) {
        int pre = i * 255 - (i * (i - 1)) / 2;
        int d = pre - target; d = (d < 0) ? -d : d;
        if (d < bd) { bd = d; best = i; }
    }
    return best;
}

// ---------------- kernel 0: angle table (cos,sin) for both rot sets ---------
__global__ __launch_bounds__(256) void k_cs(const float* __restrict__ r1,
                                            const float* __restrict__ r2,
                                            float2* __restrict__ cs) {
    int i = blockIdx.x * 256 + threadIdx.x;          // 0 .. 2*NROT-1
    float th = (i < NROT) ? r1[i] : r2[i - NROT];
    float sv, cv; sincosf(th, &sv, &cv);
    cs[i] = make_float2(cv, sv);
}

// ---------------- kernel 1: build pblk partial Givens products per matrix ---
// pblk=64: halved worst-WG serial chain, 512 WGs at 2 WGs/CU (76.9 KB LDS).
__global__ __launch_bounds__(64) void k_blocks(const float2* __restrict__ cs,
                                               float* __restrict__ bmats, int pblk) {
    __shared__ float colb[264 * 64];
    __shared__ float2 csb[256 * 4];     // single-buffered steady angles
    __shared__ float2 tri[24 * 6];      // all groups' triangle angles

    const int t = threadIdx.x;          // column within chunk
    const int bid = blockIdx.x;
    const int chunk = bid & 3;          // 0..3 (64 cols each)
    const int b = (bid >> 2) % pblk;    // 0..pblk-1
    const int set = (bid >> 2) / pblk;  // 0 = rots1, 1 = rots2
    const int col0 = chunk * 64;
    const float2* cst = cs + (size_t)set * NROT;

    const int s0 = sweep_bound(b, pblk);
    const int s1 = sweep_bound(b + 1, pblk);
    const int ngroups = (s1 - s0) >> 2;

    // zero colb (incl. pad rows 256..263), set identity diagonal
    {
        const f32x4 z = {0.f, 0.f, 0.f, 0.f};
        #pragma unroll 11
        for (int q = 0; q < 66; q++)
            *(f32x4*)&colb[(q * 64 + t) * 4] = z;
        colb[(col0 + t) * 64 + t] = 1.0f;
    }

    // stage all triangle angles (6 per group) into LDS
    for (int k = t; k < ngroups * 6; k += 64) {
        int g = k / 6, q = k - g * 6;
        int a  = (q < 3) ? 0 : ((q < 5) ? 1 : 2);
        int bb = (q < 3) ? (q + 1) : ((q < 5) ? (q - 1) : 3);
        int m0 = s0 + g * 4;
        int m = m0 + a;
        int base = m * 255 - (m * (m - 1)) / 2;
        tri[k] = cst[base - m - 1 + m0 + bb];
    }
    // single-wave WG: DS pipe is in-order per wave, no barrier needed

    float2 gv[16];                      // in-flight staging registers
    {
        const int m0g = s0;
        int offg[4];
        #pragma unroll
        for (int a = 0; a < 4; a++) {
            int m = m0g + a;
            offg[a] = m * 255 - (m * (m - 1)) / 2 - m - 1;
        }
        #pragma unroll
        for (int it = 0; it < 16; it++) {
            int k = t + it * 64;
            int jj = k >> 2, a = k & 3;
            int j = m0g + 4 + jj;
            gv[it] = (j < 256) ? cst[offg[a] + j] : make_float2(1.f, 0.f);
        }
        #pragma unroll
        for (int it = 0; it < 16; it++)
            csb[t + it * 64] = gv[it];
    }

    for (int g = 0; g < ngroups; g++) {
        const int m0 = s0 + g * 4;
        const int n_j = 252 - m0;
        const int n_p = (n_j > 0) ? ((n_j + 7) & ~7) : 0;
        const float* csbuf = (const float*)&csb[0];

        // issue NEXT group's staging loads (latency hides under this j-loop)
        const bool have_next = (g + 1 < ngroups);
        if (have_next) {
            const int m0g = m0 + 4;
            int offg[4];
            #pragma unroll
            for (int a = 0; a < 4; a++) {
                int m = m0g + a;
                offg[a] = m * 255 - (m * (m - 1)) / 2 - m - 1;
            }
            #pragma unroll
            for (int it = 0; it < 16; it++) {
                int k = t + it * 64;
                int jj = k >> 2, a = k & 3;
                int j = m0g + 4 + jj;
                gv[it] = (j < 256) ? cst[offg[a] + j] : make_float2(1.f, 0.f);
            }
        }

        float u0 = colb[(m0 + 0) * 64 + t];
        float u1 = colb[(m0 + 1) * 64 + t];
        float u2 = colb[(m0 + 2) * 64 + t];
        float u3 = colb[(m0 + 3) * 64 + t];

        {
            float2 cv; float nr;
            cv = tri[g * 6 + 0]; nr = cv.y * u0 + cv.x * u1; u0 = cv.x * u0 - cv.y * u1; u1 = nr;
            cv = tri[g * 6 + 1]; nr = cv.y * u0 + cv.x * u2; u0 = cv.x * u0 - cv.y * u2; u2 = nr;
            cv = tri[g * 6 + 2]; nr = cv.y * u0 + cv.x * u3; u0 = cv.x * u0 - cv.y * u3; u3 = nr;
            cv = tri[g * 6 + 3]; nr = cv.y * u1 + cv.x * u2; u1 = cv.x * u1 - cv.y * u2; u2 = nr;
            cv = tri[g * 6 + 4]; nr = cv.y * u1 + cv.x * u3; u1 = cv.x * u1 - cv.y * u3; u3 = nr;
            cv = tri[g * 6 + 5]; nr = cv.y * u2 + cv.x * u3; u2 = cv.x * u2 - cv.y * u3; u3 = nr;
        }

        if (n_p > 0) {
            float rbuf[8];
            f32x4 abuf[8][2];
            #pragma unroll
            for (int p = 0; p < 8; p++) {
                rbuf[p] = colb[(m0 + 4 + p) * 64 + t];
                abuf[p][0] = *(const f32x4*)&csbuf[p * 8 + 0];
                abuf[p][1] = *(const f32x4*)&csbuf[p * 8 + 4];
            }
            for (int c = 0; c < n_p; c += 8) {
                #pragma unroll
                for (int p = 0; p < 8; p++) {
                    const int j = m0 + 4 + c + p;
                    float r = rbuf[p];
                    f32x4 A01 = abuf[p][0], A23 = abuf[p][1];
                    int jn = j + 8; jn = (jn < 263) ? jn : 263;
                    int cn = c + p + 8; cn = (cn < n_p) ? cn : (n_p - 1);
                    rbuf[p] = colb[jn * 64 + t];
                    abuf[p][0] = *(const f32x4*)&csbuf[cn * 8 + 0];
                    abuf[p][1] = *(const f32x4*)&csbuf[cn * 8 + 4];
                    float nr;
                    nr = A01[1] * u0 + A01[0] * r; u0 = A01[0] * u0 - A01[1] * r; r = nr;
                    nr = A01[3] * u1 + A01[2] * r; u1 = A01[2] * u1 - A01[3] * r; r = nr;
                    nr = A23[1] * u2 + A23[0] * r; u2 = A23[0] * u2 - A23[1] * r; r = nr;
                    nr = A23[3] * u3 + A23[2] * r; u3 = A23[2] * u3 - A23[3] * r; r = nr;
                    colb[j * 64 + t] = r;
                }
            }
        }
        colb[(m0 + 0) * 64 + t] = u0;
        colb[(m0 + 1) * 64 + t] = u1;
        colb[(m0 + 2) * 64 + t] = u2;
        colb[(m0 + 3) * 64 + t] = u3;

        // commit next group's staged angles (after this group's csb reads)
        if (have_next) {
            #pragma unroll
            for (int it = 0; it < 16; it++)
                csb[t + it * 64] = gv[it];
        }
    }

    float* outm = bmats + (size_t)(set * pblk + b) * 65536;
    for (int r = 0; r < 256; r++)
        outm[(size_t)r * 256 + col0 + t] = colb[r * 64 + t];
}

// ---------------- x row-normalize -> bf16, 64 rows per item -----------------
static __device__ __forceinline__ void xnorm_item(const float* __restrict__ xg,
                                                  unsigned short* __restrict__ xbf,
                                                  int id, int tid) {
    const int w = tid >> 6, lane = tid & 63;
    const int r0 = id * 64;
    #pragma unroll 2
    for (int p = 0; p < 16; p++) {
        int row = r0 + p * 4 + w;
        f32x4 v = *(const f32x4*)&xg[(size_t)row * 256 + lane * 4];
        float s = v[0] * v[0] + v[1] * v[1] + v[2] * v[2] + v[3] * v[3];
        #pragma unroll
        for (int off = 32; off; off >>= 1) s += __shfl_xor(s, off, 64);
        float sc = 1.0f / sqrtf(s);
        unsigned short h0 = f2bf(v[0] * sc), h1 = f2bf(v[1] * sc);
        unsigned short h2 = f2bf(v[2] * sc), h3 = f2bf(v[3] * sc);
        u32x2 pk = { (unsigned)h0 | ((unsigned)h1 << 16),
                     (unsigned)h2 | ((unsigned)h3 << 16) };
        *(u32x2*)&xbf[(size_t)row * 256 + lane * 4] = pk;
    }
}

// ---------------- pipelined 64x64 matmul tile helpers -----------------------
// Single-buffered LDS (20 KB total -> 8 WGs/CU, max occupancy; R6 counters:
// the 40 KB double-buffer capped occupancy at 23.7% and the tile ran at 41%
// of HBM BW). Latency still hidden by the 2-deep register prefetch + TLP.
#define TB 2560   // 64*40 shorts per buffer

// B k-slot XOR swizzle: physical slot = s ^ ((row>>3)&3). Kills the 8-way
// bank conflict on the B commit (64 rows x stride 80 B -> 20*bn mod 32 has
// period 8); write AND read use the same mapping. [R6: 1.08M conflicts]
static __device__ __forceinline__ int bslot(int row, int s) {
    return row * 40 + ((s ^ ((row >> 3) & 3)) << 3);
}

static __device__ __forceinline__ void tile_issueA(const float* __restrict__ Am,
                                                   int tr, int kb, int tid,
                                                   f32x4 va[2]) {
    #pragma unroll
    for (int it = 0; it < 2; it++) {
        int flat = tid + it * 256;
        int r = flat >> 3, c4 = flat & 7;
        va[it] = *(const f32x4*)&Am[(size_t)(tr * 64 + r) * 256 + kb * 32 + c4 * 4];
    }
}
static __device__ __forceinline__ void tile_issueB(const float* __restrict__ Bm,
                                                   int tc, int kb, int bn, int bkq,
                                                   float vb[8]) {
    #pragma unroll
    for (int i = 0; i < 8; i++)
        vb[i] = Bm[(size_t)(kb * 32 + bkq * 8 + i) * 256 + tc * 64 + bn];
}
static __device__ __forceinline__ void tile_commit(unsigned short* __restrict__ Ahi,
                                                   unsigned short* __restrict__ Alo,
                                                   unsigned short* __restrict__ Bhi,
                                                   unsigned short* __restrict__ Blo,
                                                   int tid, int bn, int bkq,
                                                   const f32x4 va[2], const float vb[8]) {
    #pragma unroll
    for (int it = 0; it < 2; it++) {
        int flat = tid + it * 256;
        int r = flat >> 3, c4 = flat & 7;
        u32x2 hi, lo; split4(va[it], &hi, &lo);
        *(u32x2*)&Ahi[r * 40 + c4 * 4] = hi;
        *(u32x2*)&Alo[r * 40 + c4 * 4] = lo;
    }
    u32x4 hi8, lo8; split8(vb, &hi8, &lo8);
    *(u32x4*)&Bhi[bslot(bn, bkq)] = hi8;
    *(u32x4*)&Blo[bslot(bn, bkq)] = lo8;
}
static __device__ __forceinline__ void tile_mfma(const unsigned short* __restrict__ Ahi,
                                                 const unsigned short* __restrict__ Alo,
                                                 const unsigned short* __restrict__ Bhi,
                                                 const unsigned short* __restrict__ Blo,
                                                 int mh, int nh, int l15, int lq,
                                                 f32x4 acc[2][2]) {
    s16x8 ah[2], al[2], bh[2], bl[2];
    #pragma unroll
    for (int tm = 0; tm < 2; tm++) {
        ah[tm] = *(const s16x8*)&Ahi[(mh + tm * 16 + l15) * 40 + lq * 8];
        al[tm] = *(const s16x8*)&Alo[(mh + tm * 16 + l15) * 40 + lq * 8];
    }
    #pragma unroll
    for (int tn = 0; tn < 2; tn++) {
        bh[tn] = *(const s16x8*)&Bhi[bslot(nh + tn * 16 + l15, lq)];
        bl[tn] = *(const s16x8*)&Blo[bslot(nh + tn * 16 + l15, lq)];
    }
    #pragma unroll
    for (int tm = 0; tm < 2; tm++)
        #pragma unroll
        for (int tn = 0; tn < 2; tn++) {
            acc[tm][tn] = __builtin_amdgcn_mfma_f32_16x16x32_bf16(ah[tm], bh[tn], acc[tm][tn], 0, 0, 0);
            acc[tm][tn] = __builtin_amdgcn_mfma_f32_16x16x32_bf16(ah[tm], bl[tn], acc[tm][tn], 0, 0, 0);
            acc[tm][tn] = __builtin_amdgcn_mfma_f32_16x16x32_bf16(al[tm], bh[tn], acc[tm][tn], 0, 0, 0);
        }
}

// one 64x64 combine tile: dst[p] = src[2p+1] @ src[2p].
// Pipeline: commit(kb); sync; issue(kb+2); mfma(kb); sync  -- loads stay
// ~1.5 phases in flight; single LDS buffer reused across phases.
static __device__ void combine_tile(const float* __restrict__ src,
                                    float* __restrict__ dst,
                                    int half, int pblk, int bx, int by, int tid,
                                    unsigned short* Ahi, unsigned short* Alo,
                                    unsigned short* Bhi, unsigned short* Blo) {
    const int set = by / half, pidx = by % half;
    const int stride = pblk / (2 * half);
    const int s0A = sweep_bound((2 * pidx + 1) * stride, pblk);
    const float* Am = src + (size_t)(set * 2 * half + 2 * pidx + 1) * 65536;
    const float* Bm = src + (size_t)(set * 2 * half + 2 * pidx) * 65536;
    float* Dm = dst + (size_t)(set * half + pidx) * 65536;
    const int tr = bx >> 2, tc = bx & 3;

    if (tr * 64 + 64 <= s0A) {                 // pure copy tile: D = B
        #pragma unroll
        for (int it = 0; it < 4; it++) {
            int flat = tid + it * 256;
            int r = flat >> 4, c4 = flat & 15;
            size_t idx = (size_t)(tr * 64 + r) * 256 + tc * 64 + c4 * 4;
            *(f32x4*)&Dm[idx] = *(const f32x4*)&Bm[idx];
        }
        return;
    }
    const int kb0 = (tr * 64 >= s0A) ? (s0A >> 5) : 0;

    const int lane = tid & 63, w = tid >> 6;
    const int mh = (w >> 1) * 32, nh = (w & 1) * 32;
    const int l15 = lane & 15, lq = lane >> 4;
    const int bn = tid & 63, bkq = tid >> 6;

    f32x4 acc[2][2];
    #pragma unroll
    for (int i = 0; i < 2; i++)
        #pragma unroll
        for (int j = 0; j < 2; j++) acc[i][j] = (f32x4){0.f, 0.f, 0.f, 0.f};

    f32x4 vaE[2], vaO[2]; float vbE[8], vbO[8];
    tile_issueA(Am, tr, kb0, tid, vaE);
    tile_issueB(Bm, tc, kb0, bn, bkq, vbE);
    if (kb0 + 1 < 8) {
        tile_issueA(Am, tr, kb0 + 1, tid, vaO);
        tile_issueB(Bm, tc, kb0 + 1, bn, bkq, vbO);
    }

    for (int kb = kb0; kb < 8; kb++) {
        const int cur = (kb - kb0) & 1;
        if (cur == 0) {
            tile_commit(Ahi, Alo, Bhi, Blo, tid, bn, bkq, vaE, vbE);
            __syncthreads();
            if (kb + 2 < 8) {           // reuse freed E regs
                tile_issueA(Am, tr, kb + 2, tid, vaE);
                tile_issueB(Bm, tc, kb + 2, bn, bkq, vbE);
            }
        } else {
            tile_commit(Ahi, Alo, Bhi, Blo, tid, bn, bkq, vaO, vbO);
            __syncthreads();
            if (kb + 2 < 8) {
                tile_issueA(Am, tr, kb + 2, tid, vaO);
                tile_issueB(Bm, tc, kb + 2, bn, bkq, vbO);
            }
        }
        tile_mfma(Ahi, Alo, Bhi, Blo, mh, nh, l15, lq, acc);
        __syncthreads();                // protect LDS reuse by next commit
    }
    #pragma unroll
    for (int tm = 0; tm < 2; tm++)
        #pragma unroll
        for (int tn = 0; tn < 2; tn++)
            #pragma unroll
            for (int r = 0; r < 4; r++)
                Dm[(size_t)(tr * 64 + mh + tm * 16 + lq * 4 + r) * 256
                   + tc * 64 + nh + tn * 16 + l15] = acc[tm][tn][r];
}

// one 64x64 tile of AT/BT = M2 @ diag(cos|sin(phases)) @ M1 -> bf16
static __device__ void abt_tile(const float* __restrict__ mats,
                                const float* __restrict__ phases,
                                unsigned short* __restrict__ abtp,
                                int bx, int v, int tid,
                                unsigned short* Ahi, unsigned short* Alo,
                                unsigned short* Bhi, unsigned short* Blo) {
    const float* Am = mats + 65536;    // M2
    const float* Bm = mats;            // M1
    const int tr = bx >> 2, tc = bx & 3;

    const int lane = tid & 63, w = tid >> 6;
    const int mh = (w >> 1) * 32, nh = (w & 1) * 32;
    const int l15 = lane & 15, lq = lane >> 4;
    const int bn = tid & 63, bkq = tid >> 6;

    f32x4 acc[2][2];
    #pragma unroll
    for (int i = 0; i < 2; i++)
        #pragma unroll
        for (int j = 0; j < 2; j++) acc[i][j] = (f32x4){0.f, 0.f, 0.f, 0.f};

    auto issueBs = [&](int kb, float vb[8]) {
        #pragma unroll
        for (int i = 0; i < 8; i++) {
            int kg = kb * 32 + bkq * 8 + i;          // wave-uniform k index
            float ph = phases[kg];
            float sc = v ? sinf(ph) : cosf(ph);
            vb[i] = Bm[(size_t)kg * 256 + tc * 64 + bn] * sc;
        }
    };

    f32x4 vaE[2], vaO[2]; float vbE[8], vbO[8];
    tile_issueA(Am, tr, 0, tid, vaE); issueBs(0, vbE);
    tile_issueA(Am, tr, 1, tid, vaO); issueBs(1, vbO);

    for (int kb = 0; kb < 8; kb++) {
        const int cur = kb & 1;
        if (cur == 0) {
            tile_commit(Ahi, Alo, Bhi, Blo, tid, bn, bkq, vaE, vbE);
            __syncthreads();
            if (kb + 2 < 8) { tile_issueA(Am, tr, kb + 2, tid, vaE); issueBs(kb + 2, vbE); }
        } else {
            tile_commit(Ahi, Alo, Bhi, Blo, tid, bn, bkq, vaO, vbO);
            __syncthreads();
            if (kb + 2 < 8) { tile_issueA(Am, tr, kb + 2, tid, vaO); issueBs(kb + 2, vbO); }
        }
        tile_mfma(Ahi, Alo, Bhi, Blo, mh, nh, l15, lq, acc);
        __syncthreads();
    }
    #pragma unroll
    for (int tm = 0; tm < 2; tm++)
        #pragma unroll
        for (int tn = 0; tn < 2; tn++)
            #pragma unroll
            for (int r = 0; r < 4; r++)
                abtp[(size_t)(v * 256 + tr * 64 + mh + tm * 16 + lq * 4 + r) * 256
                     + tc * 64 + nh + tn * 16 + l15] = f2bf(acc[tm][tn][r]);
}

// ---------------- kernel wrappers -------------------------------------------
__global__ __launch_bounds__(256) void k_combine(const float* __restrict__ src,
                                                 float* __restrict__ dst,
                                                 int half, int pblk,
                                                 const float* __restrict__ xg,
                                                 unsigned short* __restrict__ xbf) {
    __shared__ unsigned short Ahi[TB], Alo[TB], Bhi[TB], Blo[TB];
    const int by = blockIdx.y, tid = threadIdx.x;
    if (by >= 2 * half) {
        xnorm_item(xg, xbf, (by - 2 * half) * 16 + blockIdx.x, tid);
        return;
    }
    combine_tile(src, dst, half, pblk, blockIdx.x, by, tid, Ahi, Alo, Bhi, Blo);
}

__global__ __launch_bounds__(256) void k_abt(const float* __restrict__ mats,
                                             const float* __restrict__ phases,
                                             unsigned short* __restrict__ abtp) {
    __shared__ unsigned short Ahi[TB], Alo[TB], Bhi[TB], Blo[TB];
    abt_tile(mats, phases, abtp, blockIdx.x, blockIdx.y, threadIdx.x,
             Ahi, Alo, Bhi, Blo);
}

// ---------------- kernel 4b: per-row 1/||x|| (fallback path) ----------------
__global__ __launch_bounds__(256) void k_norm(const float* __restrict__ x,
                                              float* __restrict__ invn) {
    const int row = blockIdx.x * 4 + (threadIdx.x >> 6);
    const int lane = threadIdx.x & 63;
    f32x4 v = *(const f32x4*)&x[(size_t)row * 256 + lane * 4];
    float s = v[0] * v[0] + v[1] * v[1] + v[2] * v[2] + v[3] * v[3];
    for (int off = 32; off; off >>= 1) s += __shfl_xor(s, off, 64);
    if (lane == 0) invn[row] = 1.0f / sqrtf(s);
}

// ---------------- kernel 5a: GEMM + |.|^2 from pre-converted bf16 x ---------
// XCD swizzle: remap l=(y*4+x) -> L=(l&7)*256+(l>>3): each XCD gets 64
// contiguous rb x all 4 cb -> x-tile fetched once per XCD (4 MB = L2-sized).
#define BKP 136   // padded LDS k-stride (bf16 elems)
__global__ __launch_bounds__(256) void k_gemm_bf(const unsigned short* __restrict__ xbf,
                                                 const unsigned short* __restrict__ abt,
                                                 float* __restrict__ out) {
    __shared__ unsigned short As[128 * BKP];
    __shared__ unsigned short Bs[128 * BKP];
    const int tid = threadIdx.x;
    const int l  = blockIdx.y * 4 + blockIdx.x;
    const int L  = (l & 7) * 256 + (l >> 3);
    const int cb = L & 3;               // 0..3  (64 out-cols each)
    const int rb = L >> 2;              // 0..511
    const int lane = tid & 63, w = tid >> 6;

    f32x4 acc[16];
    #pragma unroll
    for (int i = 0; i < 16; i++) acc[i] = (f32x4){0.f, 0.f, 0.f, 0.f};

    int rA[8], cA[8], grB[8];
    #pragma unroll
    for (int it = 0; it < 8; it++) {
        int flat = tid + it * 256;
        rA[it] = flat >> 4; cA[it] = flat & 15;
        int r = rA[it];
        grB[it] = (r < 64) ? (cb * 64 + r) : (256 + cb * 64 + (r - 64));
    }

    u32x4 pa[8], pb[8];
    #pragma unroll
    for (int it = 0; it < 8; it++) {
        pa[it] = *(const u32x4*)&xbf[(size_t)(rb * 128 + rA[it]) * 256 + cA[it] * 8];
        pb[it] = *(const u32x4*)&abt[(size_t)grB[it] * 256 + cA[it] * 8];
    }
    #pragma unroll
    for (int it = 0; it < 8; it++) {
        *(u32x4*)&As[rA[it] * BKP + cA[it] * 8] = pa[it];
        *(u32x4*)&Bs[rA[it] * BKP + cA[it] * 8] = pb[it];
    }
    __syncthreads();
    #pragma unroll
    for (int it = 0; it < 8; it++) {
        pa[it] = *(const u32x4*)&xbf[(size_t)(rb * 128 + rA[it]) * 256 + 128 + cA[it] * 8];
        pb[it] = *(const u32x4*)&abt[(size_t)grB[it] * 256 + 128 + cA[it] * 8];
    }

    auto compute = [&]() {
        #pragma unroll
        for (int ks = 0; ks < 4; ks++) {
            const int k0 = ks * 32 + (lane >> 4) * 8;
            s16x8 a[2], b[8];
            #pragma unroll
            for (int tm = 0; tm < 2; tm++)
                a[tm] = *(const s16x8*)&As[(w * 32 + tm * 16 + (lane & 15)) * BKP + k0];
            #pragma unroll
            for (int tn = 0; tn < 8; tn++)
                b[tn] = *(const s16x8*)&Bs[(tn * 16 + (lane & 15)) * BKP + k0];
            #pragma unroll
            for (int tm = 0; tm < 2; tm++)
                #pragma unroll
                for (int tn = 0; tn < 8; tn++)
                    acc[tm * 8 + tn] = __builtin_amdgcn_mfma_f32_16x16x32_bf16(
                        a[tm], b[tn], acc[tm * 8 + tn], 0, 0, 0);
        }
    };
    compute();                 // kb=0
    __syncthreads();
    #pragma unroll
    for (int it = 0; it < 8; it++) {
        *(u32x4*)&As[rA[it] * BKP + cA[it] * 8] = pa[it];
        *(u32x4*)&Bs[rA[it] * BKP + cA[it] * 8] = pb[it];
    }
    __syncthreads();
    compute();                 // kb=1

    const int qr = lane >> 4, c = lane & 15;
    #pragma unroll
    for (int tm = 0; tm < 2; tm++) {
        #pragma unroll
        for (int tn = 0; tn < 4; tn++) {
            f32x4 p = acc[tm * 8 + tn];
            f32x4 q = acc[tm * 8 + tn + 4];
            #pragma unroll
            for (int r = 0; r < 4; r++) {
                int m = w * 32 + tm * 16 + qr * 4 + r;
                out[(size_t)(rb * 128 + m) * 256 + cb * 64 + tn * 16 + c] =
                    p[r] * p[r] + q[r] * q[r];
            }
        }
    }
}

// ---------------- kernel 5b: GEMM + |.|^2 from fp32 x (fallback) ------------
__global__ __launch_bounds__(256) void k_gemm_f32(const float* __restrict__ x,
                                                  const unsigned short* __restrict__ abt,
                                                  const float* __restrict__ invn,
                                                  float* __restrict__ out) {
    __shared__ unsigned short As[128 * BKP];
    __shared__ unsigned short Bs[128 * BKP];
    const int tid = threadIdx.x;
    const int l  = blockIdx.y * 4 + blockIdx.x;
    const int L  = (l & 7) * 256 + (l >> 3);
    const int cb = L & 3;
    const int rb = L >> 2;
    const int lane = tid & 63, w = tid >> 6;

    f32x4 acc[16];
    #pragma unroll
    for (int i = 0; i < 16; i++) acc[i] = (f32x4){0.f, 0.f, 0.f, 0.f};

    for (int kb = 0; kb < 2; kb++) {
        __syncthreads();
        #pragma unroll
        for (int it = 0; it < 16; it++) {
            int flat = tid + it * 256;
            int r = flat >> 5, c4 = flat & 31;
            f32x4 v = *(const f32x4*)&x[(size_t)(rb * 128 + r) * 256 + kb * 128 + c4 * 4];
            float sc = invn[rb * 128 + r];
            v[0] *= sc; v[1] *= sc; v[2] *= sc; v[3] *= sc;
            unsigned short h0 = f2bf(v[0]), h1 = f2bf(v[1]);
            unsigned short h2 = f2bf(v[2]), h3 = f2bf(v[3]);
            u32x2 pk = { (unsigned)h0 | ((unsigned)h1 << 16),
                         (unsigned)h2 | ((unsigned)h3 << 16) };
            *(u32x2*)&As[r * BKP + c4 * 4] = pk;
        }
        #pragma unroll
        for (int it = 0; it < 8; it++) {
            int flat = tid + it * 256;
            int r = flat >> 4, c8 = flat & 15;
            int gr = (r < 64) ? (cb * 64 + r) : (256 + cb * 64 + (r - 64));
            u32x4 vv = *(const u32x4*)&abt[(size_t)gr * 256 + kb * 128 + c8 * 8];
            *(u32x4*)&Bs[r * BKP + c8 * 8] = vv;
        }
        __syncthreads();
        #pragma unroll
        for (int ks = 0; ks < 4; ks++) {
            const int k0 = ks * 32 + (lane >> 4) * 8;
            s16x8 a[2], b[8];
            #pragma unroll
            for (int tm = 0; tm < 2; tm++)
                a[tm] = *(const s16x8*)&As[(w * 32 + tm * 16 + (lane & 15)) * BKP + k0];
            #pragma unroll
            for (int tn = 0; tn < 8; tn++)
                b[tn] = *(const s16x8*)&Bs[(tn * 16 + (lane & 15)) * BKP + k0];
            #pragma unroll
            for (int tm = 0; tm < 2; tm++)
                #pragma unroll
                for (int tn = 0; tn < 8; tn++)
                    acc[tm * 8 + tn] = __builtin_amdgcn_mfma_f32_16x16x32_bf16(
                        a[tm], b[tn], acc[tm * 8 + tn], 0, 0, 0);
        }
    }

    const int qr = lane >> 4, c = lane & 15;
    #pragma unroll
    for (int tm = 0; tm < 2; tm++) {
        #pragma unroll
        for (int tn = 0; tn < 4; tn++) {
            f32x4 p = acc[tm * 8 + tn];
            f32x4 q = acc[tm * 8 + tn + 4];
            #pragma unroll
            for (int r = 0; r < 4; r++) {
                int m = w * 32 + tm * 16 + qr * 4 + r;
                out[(size_t)(rb * 128 + m) * 256 + cb * 64 + tn * 16 + c] =
                    p[r] * p[r] + q[r] * q[r];
            }
        }
    }
}

// ---------------- host ------------------------------------------------------
extern "C" void kernel_launch(void* const* d_in, const int* in_sizes, int n_in,
                              void* d_out, int out_size, void* d_ws, size_t ws_size,
                              hipStream_t stream) {
    (void)in_sizes; (void)n_in; (void)out_size;
    const float* x      = (const float*)d_in[0];
    const float* rots1  = (const float*)d_in[1];
    const float* phases = (const float*)d_in[2];
    const float* rots2  = (const float*)d_in[3];
    float* out = (float*)d_out;
    char* ws = (char*)d_ws;

    const size_t MAT = 262144;                 // 256x256 fp32
    int pblk = 64;
    while (pblk > 16 &&
           (size_t)3 * pblk * MAT + 2 * MAT + (size_t)BATCH * 512 > ws_size)
        pblk >>= 1;
    const size_t offA   = 0;
    const size_t offB   = offA + (size_t)2 * pblk * MAT;   // A: 2*pblk mats
    const size_t offABT = offB + (size_t)pblk * MAT;       // B: pblk mats
    const size_t offINV = offABT + MAT;
    const size_t offXBF = offINV + MAT;
    const bool use_xbf = (offXBF + (size_t)BATCH * 512) <= ws_size;

    float*          A    = (float*)(ws + offA);
    float*          B    = (float*)(ws + offB);
    unsigned short* abt  = (unsigned short*)(ws + offABT);
    float*          invn = (float*)(ws + offINV);
    unsigned short* xbf  = (unsigned short*)(ws + offXBF);
    // cos/sin table overlays the B ping-pong buffer: written by k_cs, read by
    // k_blocks, dead by the time combine round 1 overwrites B.
    float2*         cs   = (float2*)(ws + offB);

    k_cs<<<(2 * NROT) / 256, 256, 0, stream>>>(rots1, rots2, cs);
    k_blocks<<<8 * pblk, 64, 0, stream>>>(cs, A, pblk);

    float* srcp = A; float* dstp = B;
    bool first = true;
    for (int half = pblk / 2; half >= 1; half >>= 1) {
        const int xny = (first && use_xbf) ? 64 : 0;
        k_combine<<<dim3(16, 2 * half + xny), 256, 0, stream>>>(srcp, dstp, half,
                                                                pblk, x, xbf);
        float* tmp = srcp; srcp = dstp; dstp = tmp;
        first = false;
    }
    k_abt<<<dim3(16, 2), 256, 0, stream>>>(srcp, phases, abt);

    if (use_xbf) {
        k_gemm_bf<<<dim3(4, BATCH / 128), 256, 0, stream>>>(xbf, abt, out);
    } else {
        k_norm<<<BATCH / 4, 256, 0, stream>>>(x, invn);
        k_gemm_f32<<<dim3(4, BATCH / 128), 256, 0, stream>>>(x, abt, invn, out);
    }
}

// Round 8
// 262.107 us; speedup vs baseline: 1.0857x; 1.0676x over previous
//
#include <hip/hip_runtime.h>
#include <stdint.h>
#include <math.h>

#define NDIM 256
#define BATCH 65536
#define NROT 32640          // 256*255/2

typedef float  f32x4 __attribute__((ext_vector_type(4)));
typedef short  s16x8 __attribute__((ext_vector_type(8)));
typedef unsigned int u32x4 __attribute__((ext_vector_type(4)));
typedef unsigned int u32x2 __attribute__((ext_vector_type(2)));

// round-to-nearest-even float -> bf16 bits
static __device__ __forceinline__ unsigned short f2bf(float f) {
    unsigned int u = __float_as_uint(f);
    u += 0x7fffu + ((u >> 16) & 1u);
    return (unsigned short)(u >> 16);
}
static __device__ __forceinline__ float bf2f(unsigned short h) {
    return __uint_as_float(((unsigned)h) << 16);
}

// split 4 fp32 -> bf16 hi + bf16 lo (packed).  a ~= hi + lo, |err| ~ 2^-18|a|
static __device__ __forceinline__ void split4(f32x4 v, u32x2* hi, u32x2* lo) {
    unsigned short h[4], l[4];
    #pragma unroll
    for (int i = 0; i < 4; i++) {
        h[i] = f2bf(v[i]);
        l[i] = f2bf(v[i] - bf2f(h[i]));
    }
    *hi = (u32x2){ (unsigned)h[0] | ((unsigned)h[1] << 16),
                   (unsigned)h[2] | ((unsigned)h[3] << 16) };
    *lo = (u32x2){ (unsigned)l[0] | ((unsigned)l[1] << 16),
                   (unsigned)l[2] | ((unsigned)l[3] << 16) };
}
static __device__ __forceinline__ void split8(const float* v, u32x4* hi, u32x4* lo) {
    unsigned short h[8], l[8];
    #pragma unroll
    for (int i = 0; i < 8; i++) {
        h[i] = f2bf(v[i]);
        l[i] = f2bf(v[i] - bf2f(h[i]));
    }
    *hi = (u32x4){ (unsigned)h[0] | ((unsigned)h[1] << 16),
                   (unsigned)h[2] | ((unsigned)h[3] << 16),
                   (unsigned)h[4] | ((unsigned)h[5] << 16),
                   (unsigned)h[6] | ((unsigned)h[7] << 16) };
    *lo = (u32x4){ (unsigned)l[0] | ((unsigned)l[1] << 16),
                   (unsigned)l[2] | ((unsigned)l[3] << 16),
                   (unsigned)l[4] | ((unsigned)l[5] << 16),
                   (unsigned)l[6] | ((unsigned)l[7] << 16) };
}

// nearest 4-aligned sweep boundary to k*(NROT/pblk); shared by k_blocks
// and k_combine (the block-diagonal skip logic depends on agreement).
static __device__ __forceinline__ int sweep_bound(int k, int pblk) {
    int target = k * (NROT / pblk);
    int best = 0, bd = 0x7fffffff;
    for (int i = 0; i <= 256; i += 4) {
        int pre = i * 255 - (i * (i - 1)) / 2;
        int d = pre - target; d = (d < 0) ? -d : d;
        if (d < bd) { bd = d; best = i; }
    }
    return best;
}

// ---------------- kernel 0: angle table (cos,sin) for both rot sets ---------
__global__ __launch_bounds__(256) void k_cs(const float* __restrict__ r1,
                                            const float* __restrict__ r2,
                                            float2* __restrict__ cs) {
    int i = blockIdx.x * 256 + threadIdx.x;          // 0 .. 2*NROT-1
    float th = (i < NROT) ? r1[i] : r2[i - NROT];
    float sv, cv; sincosf(th, &sv, &cv);
    cs[i] = make_float2(cv, sv);
}

// ---------------- kernel 1: build pblk partial Givens products per matrix ---
// pblk=64: halved worst-WG serial chain, 512 WGs at 2 WGs/CU (76.9 KB LDS).
__global__ __launch_bounds__(64) void k_blocks(const float2* __restrict__ cs,
                                               float* __restrict__ bmats, int pblk) {
    __shared__ float colb[264 * 64];
    __shared__ float2 csb[256 * 4];     // single-buffered steady angles
    __shared__ float2 tri[24 * 6];      // all groups' triangle angles

    const int t = threadIdx.x;          // column within chunk
    const int bid = blockIdx.x;
    const int chunk = bid & 3;          // 0..3 (64 cols each)
    const int b = (bid >> 2) % pblk;    // 0..pblk-1
    const int set = (bid >> 2) / pblk;  // 0 = rots1, 1 = rots2
    const int col0 = chunk * 64;
    const float2* cst = cs + (size_t)set * NROT;

    const int s0 = sweep_bound(b, pblk);
    const int s1 = sweep_bound(b + 1, pblk);
    const int ngroups = (s1 - s0) >> 2;

    // zero colb (incl. pad rows 256..263), set identity diagonal
    {
        const f32x4 z = {0.f, 0.f, 0.f, 0.f};
        #pragma unroll 11
        for (int q = 0; q < 66; q++)
            *(f32x4*)&colb[(q * 64 + t) * 4] = z;
        colb[(col0 + t) * 64 + t] = 1.0f;
    }

    // stage all triangle angles (6 per group) into LDS
    for (int k = t; k < ngroups * 6; k += 64) {
        int g = k / 6, q = k - g * 6;
        int a  = (q < 3) ? 0 : ((q < 5) ? 1 : 2);
        int bb = (q < 3) ? (q + 1) : ((q < 5) ? (q - 1) : 3);
        int m0 = s0 + g * 4;
        int m = m0 + a;
        int base = m * 255 - (m * (m - 1)) / 2;
        tri[k] = cst[base - m - 1 + m0 + bb];
    }
    // single-wave WG: DS pipe is in-order per wave, no barrier needed

    float2 gv[16];                      // in-flight staging registers
    {
        const int m0g = s0;
        int offg[4];
        #pragma unroll
        for (int a = 0; a < 4; a++) {
            int m = m0g + a;
            offg[a] = m * 255 - (m * (m - 1)) / 2 - m - 1;
        }
        #pragma unroll
        for (int it = 0; it < 16; it++) {
            int k = t + it * 64;
            int jj = k >> 2, a = k & 3;
            int j = m0g + 4 + jj;
            gv[it] = (j < 256) ? cst[offg[a] + j] : make_float2(1.f, 0.f);
        }
        #pragma unroll
        for (int it = 0; it < 16; it++)
            csb[t + it * 64] = gv[it];
    }

    for (int g = 0; g < ngroups; g++) {
        const int m0 = s0 + g * 4;
        const int n_j = 252 - m0;
        const int n_p = (n_j > 0) ? ((n_j + 7) & ~7) : 0;
        const float* csbuf = (const float*)&csb[0];

        // issue NEXT group's staging loads (latency hides under this j-loop)
        const bool have_next = (g + 1 < ngroups);
        if (have_next) {
            const int m0g = m0 + 4;
            int offg[4];
            #pragma unroll
            for (int a = 0; a < 4; a++) {
                int m = m0g + a;
                offg[a] = m * 255 - (m * (m - 1)) / 2 - m - 1;
            }
            #pragma unroll
            for (int it = 0; it < 16; it++) {
                int k = t + it * 64;
                int jj = k >> 2, a = k & 3;
                int j = m0g + 4 + jj;
                gv[it] = (j < 256) ? cst[offg[a] + j] : make_float2(1.f, 0.f);
            }
        }

        float u0 = colb[(m0 + 0) * 64 + t];
        float u1 = colb[(m0 + 1) * 64 + t];
        float u2 = colb[(m0 + 2) * 64 + t];
        float u3 = colb[(m0 + 3) * 64 + t];

        {
            float2 cv; float nr;
            cv = tri[g * 6 + 0]; nr = cv.y * u0 + cv.x * u1; u0 = cv.x * u0 - cv.y * u1; u1 = nr;
            cv = tri[g * 6 + 1]; nr = cv.y * u0 + cv.x * u2; u0 = cv.x * u0 - cv.y * u2; u2 = nr;
            cv = tri[g * 6 + 2]; nr = cv.y * u0 + cv.x * u3; u0 = cv.x * u0 - cv.y * u3; u3 = nr;
            cv = tri[g * 6 + 3]; nr = cv.y * u1 + cv.x * u2; u1 = cv.x * u1 - cv.y * u2; u2 = nr;
            cv = tri[g * 6 + 4]; nr = cv.y * u1 + cv.x * u3; u1 = cv.x * u1 - cv.y * u3; u3 = nr;
            cv = tri[g * 6 + 5]; nr = cv.y * u2 + cv.x * u3; u2 = cv.x * u2 - cv.y * u3; u3 = nr;
        }

        if (n_p > 0) {
            float rbuf[8];
            f32x4 abuf[8][2];
            #pragma unroll
            for (int p = 0; p < 8; p++) {
                rbuf[p] = colb[(m0 + 4 + p) * 64 + t];
                abuf[p][0] = *(const f32x4*)&csbuf[p * 8 + 0];
                abuf[p][1] = *(const f32x4*)&csbuf[p * 8 + 4];
            }
            for (int c = 0; c < n_p; c += 8) {
                #pragma unroll
                for (int p = 0; p < 8; p++) {
                    const int j = m0 + 4 + c + p;
                    float r = rbuf[p];
                    f32x4 A01 = abuf[p][0], A23 = abuf[p][1];
                    int jn = j + 8; jn = (jn < 263) ? jn : 263;
                    int cn = c + p + 8; cn = (cn < n_p) ? cn : (n_p - 1);
                    rbuf[p] = colb[jn * 64 + t];
                    abuf[p][0] = *(const f32x4*)&csbuf[cn * 8 + 0];
                    abuf[p][1] = *(const f32x4*)&csbuf[cn * 8 + 4];
                    float nr;
                    nr = A01[1] * u0 + A01[0] * r; u0 = A01[0] * u0 - A01[1] * r; r = nr;
                    nr = A01[3] * u1 + A01[2] * r; u1 = A01[2] * u1 - A01[3] * r; r = nr;
                    nr = A23[1] * u2 + A23[0] * r; u2 = A23[0] * u2 - A23[1] * r; r = nr;
                    nr = A23[3] * u3 + A23[2] * r; u3 = A23[2] * u3 - A23[3] * r; r = nr;
                    colb[j * 64 + t] = r;
                }
            }
        }
        colb[(m0 + 0) * 64 + t] = u0;
        colb[(m0 + 1) * 64 + t] = u1;
        colb[(m0 + 2) * 64 + t] = u2;
        colb[(m0 + 3) * 64 + t] = u3;

        // commit next group's staged angles (after this group's csb reads)
        if (have_next) {
            #pragma unroll
            for (int it = 0; it < 16; it++)
                csb[t + it * 64] = gv[it];
        }
    }

    float* outm = bmats + (size_t)(set * pblk + b) * 65536;
    for (int r = 0; r < 256; r++)
        outm[(size_t)r * 256 + col0 + t] = colb[r * 64 + t];
}

// ---------------- x row-normalize -> bf16, 64 rows per item -----------------
static __device__ __forceinline__ void xnorm_item(const float* __restrict__ xg,
                                                  unsigned short* __restrict__ xbf,
                                                  int id, int tid) {
    const int w = tid >> 6, lane = tid & 63;
    const int r0 = id * 64;
    #pragma unroll 2
    for (int p = 0; p < 16; p++) {
        int row = r0 + p * 4 + w;
        f32x4 v = *(const f32x4*)&xg[(size_t)row * 256 + lane * 4];
        float s = v[0] * v[0] + v[1] * v[1] + v[2] * v[2] + v[3] * v[3];
        #pragma unroll
        for (int off = 32; off; off >>= 1) s += __shfl_xor(s, off, 64);
        float sc = 1.0f / sqrtf(s);
        unsigned short h0 = f2bf(v[0] * sc), h1 = f2bf(v[1] * sc);
        unsigned short h2 = f2bf(v[2] * sc), h3 = f2bf(v[3] * sc);
        u32x2 pk = { (unsigned)h0 | ((unsigned)h1 << 16),
                     (unsigned)h2 | ((unsigned)h3 << 16) };
        *(u32x2*)&xbf[(size_t)row * 256 + lane * 4] = pk;
    }
}

// ---------------- pipelined 64x64 matmul tile helpers -----------------------
// Single-buffered LDS (20 KB total -> 8 WGs/CU); 2-deep register prefetch.
#define TB 2560   // 64*40 shorts per buffer

// B k-slot XOR swizzle: physical slot = s ^ ((row>>3)&3). Kills the 8-way
// bank conflict on the B commit; write AND read use the same mapping.
static __device__ __forceinline__ int bslot(int row, int s) {
    return row * 40 + ((s ^ ((row >> 3) & 3)) << 3);
}

static __device__ __forceinline__ void tile_issueA(const float* __restrict__ Am,
                                                   int tr, int kb, int tid,
                                                   f32x4 va[2]) {
    #pragma unroll
    for (int it = 0; it < 2; it++) {
        int flat = tid + it * 256;
        int r = flat >> 3, c4 = flat & 7;
        va[it] = *(const f32x4*)&Am[(size_t)(tr * 64 + r) * 256 + kb * 32 + c4 * 4];
    }
}
static __device__ __forceinline__ void tile_issueB(const float* __restrict__ Bm,
                                                   int tc, int kb, int bn, int bkq,
                                                   float vb[8]) {
    #pragma unroll
    for (int i = 0; i < 8; i++)
        vb[i] = Bm[(size_t)(kb * 32 + bkq * 8 + i) * 256 + tc * 64 + bn];
}
static __device__ __forceinline__ void tile_commit(unsigned short* __restrict__ Ahi,
                                                   unsigned short* __restrict__ Alo,
                                                   unsigned short* __restrict__ Bhi,
                                                   unsigned short* __restrict__ Blo,
                                                   int tid, int bn, int bkq,
                                                   const f32x4 va[2], const float vb[8]) {
    #pragma unroll
    for (int it = 0; it < 2; it++) {
        int flat = tid + it * 256;
        int r = flat >> 3, c4 = flat & 7;
        u32x2 hi, lo; split4(va[it], &hi, &lo);
        *(u32x2*)&Ahi[r * 40 + c4 * 4] = hi;
        *(u32x2*)&Alo[r * 40 + c4 * 4] = lo;
    }
    u32x4 hi8, lo8; split8(vb, &hi8, &lo8);
    *(u32x4*)&Bhi[bslot(bn, bkq)] = hi8;
    *(u32x4*)&Blo[bslot(bn, bkq)] = lo8;
}
static __device__ __forceinline__ void tile_mfma(const unsigned short* __restrict__ Ahi,
                                                 const unsigned short* __restrict__ Alo,
                                                 const unsigned short* __restrict__ Bhi,
                                                 const unsigned short* __restrict__ Blo,
                                                 int mh, int nh, int l15, int lq,
                                                 f32x4 acc[2][2]) {
    s16x8 ah[2], al[2], bh[2], bl[2];
    #pragma unroll
    for (int tm = 0; tm < 2; tm++) {
        ah[tm] = *(const s16x8*)&Ahi[(mh + tm * 16 + l15) * 40 + lq * 8];
        al[tm] = *(const s16x8*)&Alo[(mh + tm * 16 + l15) * 40 + lq * 8];
    }
    #pragma unroll
    for (int tn = 0; tn < 2; tn++) {
        bh[tn] = *(const s16x8*)&Bhi[bslot(nh + tn * 16 + l15, lq)];
        bl[tn] = *(const s16x8*)&Blo[bslot(nh + tn * 16 + l15, lq)];
    }
    #pragma unroll
    for (int tm = 0; tm < 2; tm++)
        #pragma unroll
        for (int tn = 0; tn < 2; tn++) {
            acc[tm][tn] = __builtin_amdgcn_mfma_f32_16x16x32_bf16(ah[tm], bh[tn], acc[tm][tn], 0, 0, 0);
            acc[tm][tn] = __builtin_amdgcn_mfma_f32_16x16x32_bf16(ah[tm], bl[tn], acc[tm][tn], 0, 0, 0);
            acc[tm][tn] = __builtin_amdgcn_mfma_f32_16x16x32_bf16(al[tm], bh[tn], acc[tm][tn], 0, 0, 0);
        }
}

// one 64x64 combine tile: dst[p] = src[2p+1] @ src[2p].
// Pipeline: commit(kb); sync; issue(kb+2); mfma(kb); sync.
static __device__ void combine_tile(const float* __restrict__ src,
                                    float* __restrict__ dst,
                                    int half, int pblk, int bx, int by, int tid,
                                    unsigned short* Ahi, unsigned short* Alo,
                                    unsigned short* Bhi, unsigned short* Blo) {
    const int set = by / half, pidx = by % half;
    const int stride = pblk / (2 * half);
    const int s0A = sweep_bound((2 * pidx + 1) * stride, pblk);
    const float* Am = src + (size_t)(set * 2 * half + 2 * pidx + 1) * 65536;
    const float* Bm = src + (size_t)(set * 2 * half + 2 * pidx) * 65536;
    float* Dm = dst + (size_t)(set * half + pidx) * 65536;
    const int tr = bx >> 2, tc = bx & 3;

    if (tr * 64 + 64 <= s0A) {                 // pure copy tile: D = B
        #pragma unroll
        for (int it = 0; it < 4; it++) {
            int flat = tid + it * 256;
            int r = flat >> 4, c4 = flat & 15;
            size_t idx = (size_t)(tr * 64 + r) * 256 + tc * 64 + c4 * 4;
            *(f32x4*)&Dm[idx] = *(const f32x4*)&Bm[idx];
        }
        return;
    }
    const int kb0 = (tr * 64 >= s0A) ? (s0A >> 5) : 0;

    const int lane = tid & 63, w = tid >> 6;
    const int mh = (w >> 1) * 32, nh = (w & 1) * 32;
    const int l15 = lane & 15, lq = lane >> 4;
    const int bn = tid & 63, bkq = tid >> 6;

    f32x4 acc[2][2];
    #pragma unroll
    for (int i = 0; i < 2; i++)
        #pragma unroll
        for (int j = 0; j < 2; j++) acc[i][j] = (f32x4){0.f, 0.f, 0.f, 0.f};

    f32x4 vaE[2], vaO[2]; float vbE[8], vbO[8];
    tile_issueA(Am, tr, kb0, tid, vaE);
    tile_issueB(Bm, tc, kb0, bn, bkq, vbE);
    if (kb0 + 1 < 8) {
        tile_issueA(Am, tr, kb0 + 1, tid, vaO);
        tile_issueB(Bm, tc, kb0 + 1, bn, bkq, vbO);
    }

    for (int kb = kb0; kb < 8; kb++) {
        const int cur = (kb - kb0) & 1;
        if (cur == 0) {
            tile_commit(Ahi, Alo, Bhi, Blo, tid, bn, bkq, vaE, vbE);
            __syncthreads();
            if (kb + 2 < 8) {           // reuse freed E regs
                tile_issueA(Am, tr, kb + 2, tid, vaE);
                tile_issueB(Bm, tc, kb + 2, bn, bkq, vbE);
            }
        } else {
            tile_commit(Ahi, Alo, Bhi, Blo, tid, bn, bkq, vaO, vbO);
            __syncthreads();
            if (kb + 2 < 8) {
                tile_issueA(Am, tr, kb + 2, tid, vaO);
                tile_issueB(Bm, tc, kb + 2, bn, bkq, vbO);
            }
        }
        tile_mfma(Ahi, Alo, Bhi, Blo, mh, nh, l15, lq, acc);
        __syncthreads();                // protect LDS reuse by next commit
    }
    #pragma unroll
    for (int tm = 0; tm < 2; tm++)
        #pragma unroll
        for (int tn = 0; tn < 2; tn++)
            #pragma unroll
            for (int r = 0; r < 4; r++)
                Dm[(size_t)(tr * 64 + mh + tm * 16 + lq * 4 + r) * 256
                   + tc * 64 + nh + tn * 16 + l15] = acc[tm][tn][r];
}

// ---------------- kernel wrappers -------------------------------------------
__global__ __launch_bounds__(256) void k_combine(const float* __restrict__ src,
                                                 float* __restrict__ dst,
                                                 int half, int pblk,
                                                 const float* __restrict__ xg,
                                                 unsigned short* __restrict__ xbf) {
    __shared__ unsigned short Ahi[TB], Alo[TB], Bhi[TB], Blo[TB];
    const int by = blockIdx.y, tid = threadIdx.x;
    if (by >= 2 * half) {
        xnorm_item(xg, xbf, (by - 2 * half) * 16 + blockIdx.x, tid);
        return;
    }
    combine_tile(src, dst, half, pblk, blockIdx.x, by, tid, Ahi, Alo, Bhi, Blo);
}

// ---------------- kernel 3a: K-split ABT partials ---------------------------
// ABT = M2 @ diag(cos|sin(phases)) @ M1, K-split 8 ways (R7: the monolithic
// 32-WG k_abt ran 55us at 1.3% occupancy -- pure serial-phase latency).
// grid (16 tiles, 2 v, 8 kz) = 256 WGs; each WG does ONE k-phase and writes
// an fp32 partial. Linear in K, so sum of partials == full result.
__global__ __launch_bounds__(256) void k_abt_part(const float* __restrict__ mats,
                                                  const float* __restrict__ phases,
                                                  float* __restrict__ part) {
    __shared__ unsigned short Ahi[TB], Alo[TB], Bhi[TB], Blo[TB];
    const float* Am = mats + 65536;    // M2
    const float* Bm = mats;            // M1
    const int tid = threadIdx.x;
    const int bx = blockIdx.x;         // 0..15 output tile
    const int v  = blockIdx.y;         // 0: cos, 1: sin
    const int kb = blockIdx.z;         // 0..7 K-chunk (32 wide)
    const int tr = bx >> 2, tc = bx & 3;

    const int lane = tid & 63, w = tid >> 6;
    const int mh = (w >> 1) * 32, nh = (w & 1) * 32;
    const int l15 = lane & 15, lq = lane >> 4;
    const int bn = tid & 63, bkq = tid >> 6;

    f32x4 va[2]; float vb[8];
    tile_issueA(Am, tr, kb, tid, va);
    #pragma unroll
    for (int i = 0; i < 8; i++) {
        int kg = kb * 32 + bkq * 8 + i;            // wave-uniform k index
        float ph = phases[kg];
        float sc = v ? sinf(ph) : cosf(ph);
        vb[i] = Bm[(size_t)kg * 256 + tc * 64 + bn] * sc;
    }

    f32x4 acc[2][2];
    #pragma unroll
    for (int i = 0; i < 2; i++)
        #pragma unroll
        for (int j = 0; j < 2; j++) acc[i][j] = (f32x4){0.f, 0.f, 0.f, 0.f};

    tile_commit(Ahi, Alo, Bhi, Blo, tid, bn, bkq, va, vb);
    __syncthreads();
    tile_mfma(Ahi, Alo, Bhi, Blo, mh, nh, l15, lq, acc);

    float* pp = part + (size_t)(kb * 2 + v) * 65536;   // [kz][v][256][256]
    #pragma unroll
    for (int tm = 0; tm < 2; tm++)
        #pragma unroll
        for (int tn = 0; tn < 2; tn++)
            #pragma unroll
            for (int r = 0; r < 4; r++)
                pp[(size_t)(tr * 64 + mh + tm * 16 + lq * 4 + r) * 256
                   + tc * 64 + nh + tn * 16 + l15] = acc[tm][tn][r];
}

// ---------------- kernel 3b: reduce 8 partials -> bf16 abt ------------------
__global__ __launch_bounds__(256) void k_abt_red(const float* __restrict__ part,
                                                 unsigned short* __restrict__ abt) {
    const int e = (blockIdx.x * 256 + threadIdx.x) * 4;   // over [2][65536]
    f32x4 s = {0.f, 0.f, 0.f, 0.f};
    #pragma unroll
    for (int kz = 0; kz < 8; kz++)
        s += *(const f32x4*)&part[(size_t)kz * 131072 + e];
    unsigned short h0 = f2bf(s[0]), h1 = f2bf(s[1]);
    unsigned short h2 = f2bf(s[2]), h3 = f2bf(s[3]);
    u32x2 pk = { (unsigned)h0 | ((unsigned)h1 << 16),
                 (unsigned)h2 | ((unsigned)h3 << 16) };
    *(u32x2*)&abt[e] = pk;
}

// ---------------- kernel 4b: per-row 1/||x|| (fallback path) ----------------
__global__ __launch_bounds__(256) void k_norm(const float* __restrict__ x,
                                              float* __restrict__ invn) {
    const int row = blockIdx.x * 4 + (threadIdx.x >> 6);
    const int lane = threadIdx.x & 63;
    f32x4 v = *(const f32x4*)&x[(size_t)row * 256 + lane * 4];
    float s = v[0] * v[0] + v[1] * v[1] + v[2] * v[2] + v[3] * v[3];
    for (int off = 32; off; off >>= 1) s += __shfl_xor(s, off, 64);
    if (lane == 0) invn[row] = 1.0f / sqrtf(s);
}

// ---------------- kernel 5a: GEMM + |.|^2 from pre-converted bf16 x ---------
// XCD swizzle: remap l=(y*4+x) -> L=(l&7)*256+(l>>3): each XCD gets 64
// contiguous rb x all 4 cb -> x-tile fetched once per XCD (4 MB = L2-sized).
#define BKP 136   // padded LDS k-stride (bf16 elems)
__global__ __launch_bounds__(256) void k_gemm_bf(const unsigned short* __restrict__ xbf,
                                                 const unsigned short* __restrict__ abt,
                                                 float* __restrict__ out) {
    __shared__ unsigned short As[128 * BKP];
    __shared__ unsigned short Bs[128 * BKP];
    const int tid = threadIdx.x;
    const int l  = blockIdx.y * 4 + blockIdx.x;
    const int L  = (l & 7) * 256 + (l >> 3);
    const int cb = L & 3;               // 0..3  (64 out-cols each)
    const int rb = L >> 2;              // 0..511
    const int lane = tid & 63, w = tid >> 6;

    f32x4 acc[16];
    #pragma unroll
    for (int i = 0; i < 16; i++) acc[i] = (f32x4){0.f, 0.f, 0.f, 0.f};

    int rA[8], cA[8], grB[8];
    #pragma unroll
    for (int it = 0; it < 8; it++) {
        int flat = tid + it * 256;
        rA[it] = flat >> 4; cA[it] = flat & 15;
        int r = rA[it];
        grB[it] = (r < 64) ? (cb * 64 + r) : (256 + cb * 64 + (r - 64));
    }

    u32x4 pa[8], pb[8];
    #pragma unroll
    for (int it = 0; it < 8; it++) {
        pa[it] = *(const u32x4*)&xbf[(size_t)(rb * 128 + rA[it]) * 256 + cA[it] * 8];
        pb[it] = *(const u32x4*)&abt[(size_t)grB[it] * 256 + cA[it] * 8];
    }
    #pragma unroll
    for (int it = 0; it < 8; it++) {
        *(u32x4*)&As[rA[it] * BKP + cA[it] * 8] = pa[it];
        *(u32x4*)&Bs[rA[it] * BKP + cA[it] * 8] = pb[it];
    }
    __syncthreads();
    #pragma unroll
    for (int it = 0; it < 8; it++) {
        pa[it] = *(const u32x4*)&xbf[(size_t)(rb * 128 + rA[it]) * 256 + 128 + cA[it] * 8];
        pb[it] = *(const u32x4*)&abt[(size_t)grB[it] * 256 + 128 + cA[it] * 8];
    }

    auto compute = [&]() {
        #pragma unroll
        for (int ks = 0; ks < 4; ks++) {
            const int k0 = ks * 32 + (lane >> 4) * 8;
            s16x8 a[2], b[8];
            #pragma unroll
            for (int tm = 0; tm < 2; tm++)
                a[tm] = *(const s16x8*)&As[(w * 32 + tm * 16 + (lane & 15)) * BKP + k0];
            #pragma unroll
            for (int tn = 0; tn < 8; tn++)
                b[tn] = *(const s16x8*)&Bs[(tn * 16 + (lane & 15)) * BKP + k0];
            #pragma unroll
            for (int tm = 0; tm < 2; tm++)
                #pragma unroll
                for (int tn = 0; tn < 8; tn++)
                    acc[tm * 8 + tn] = __builtin_amdgcn_mfma_f32_16x16x32_bf16(
                        a[tm], b[tn], acc[tm * 8 + tn], 0, 0, 0);
        }
    };
    compute();                 // kb=0
    __syncthreads();
    #pragma unroll
    for (int it = 0; it < 8; it++) {
        *(u32x4*)&As[rA[it] * BKP + cA[it] * 8] = pa[it];
        *(u32x4*)&Bs[rA[it] * BKP + cA[it] * 8] = pb[it];
    }
    __syncthreads();
    compute();                 // kb=1

    const int qr = lane >> 4, c = lane & 15;
    #pragma unroll
    for (int tm = 0; tm < 2; tm++) {
        #pragma unroll
        for (int tn = 0; tn < 4; tn++) {
            f32x4 p = acc[tm * 8 + tn];
            f32x4 q = acc[tm * 8 + tn + 4];
            #pragma unroll
            for (int r = 0; r < 4; r++) {
                int m = w * 32 + tm * 16 + qr * 4 + r;
                out[(size_t)(rb * 128 + m) * 256 + cb * 64 + tn * 16 + c] =
                    p[r] * p[r] + q[r] * q[r];
            }
        }
    }
}

// ---------------- kernel 5b: GEMM + |.|^2 from fp32 x (fallback) ------------
__global__ __launch_bounds__(256) void k_gemm_f32(const float* __restrict__ x,
                                                  const unsigned short* __restrict__ abt,
                                                  const float* __restrict__ invn,
                                                  float* __restrict__ out) {
    __shared__ unsigned short As[128 * BKP];
    __shared__ unsigned short Bs[128 * BKP];
    const int tid = threadIdx.x;
    const int l  = blockIdx.y * 4 + blockIdx.x;
    const int L  = (l & 7) * 256 + (l >> 3);
    const int cb = L & 3;
    const int rb = L >> 2;
    const int lane = tid & 63, w = tid >> 6;

    f32x4 acc[16];
    #pragma unroll
    for (int i = 0; i < 16; i++) acc[i] = (f32x4){0.f, 0.f, 0.f, 0.f};

    for (int kb = 0; kb < 2; kb++) {
        __syncthreads();
        #pragma unroll
        for (int it = 0; it < 16; it++) {
            int flat = tid + it * 256;
            int r = flat >> 5, c4 = flat & 31;
            f32x4 v = *(const f32x4*)&x[(size_t)(rb * 128 + r) * 256 + kb * 128 + c4 * 4];
            float sc = invn[rb * 128 + r];
            v[0] *= sc; v[1] *= sc; v[2] *= sc; v[3] *= sc;
            unsigned short h0 = f2bf(v[0]), h1 = f2bf(v[1]);
            unsigned short h2 = f2bf(v[2]), h3 = f2bf(v[3]);
            u32x2 pk = { (unsigned)h0 | ((unsigned)h1 << 16),
                         (unsigned)h2 | ((unsigned)h3 << 16) };
            *(u32x2*)&As[r * BKP + c4 * 4] = pk;
        }
        #pragma unroll
        for (int it = 0; it < 8; it++) {
            int flat = tid + it * 256;
            int r = flat >> 4, c8 = flat & 15;
            int gr = (r < 64) ? (cb * 64 + r) : (256 + cb * 64 + (r - 64));
            u32x4 vv = *(const u32x4*)&abt[(size_t)gr * 256 + kb * 128 + c8 * 8];
            *(u32x4*)&Bs[r * BKP + c8 * 8] = vv;
        }
        __syncthreads();
        #pragma unroll
        for (int ks = 0; ks < 4; ks++) {
            const int k0 = ks * 32 + (lane >> 4) * 8;
            s16x8 a[2], b[8];
            #pragma unroll
            for (int tm = 0; tm < 2; tm++)
                a[tm] = *(const s16x8*)&As[(w * 32 + tm * 16 + (lane & 15)) * BKP + k0];
            #pragma unroll
            for (int tn = 0; tn < 8; tn++)
                b[tn] = *(const s16x8*)&Bs[(tn * 16 + (lane & 15)) * BKP + k0];
            #pragma unroll
            for (int tm = 0; tm < 2; tm++)
                #pragma unroll
                for (int tn = 0; tn < 8; tn++)
                    acc[tm * 8 + tn] = __builtin_amdgcn_mfma_f32_16x16x32_bf16(
                        a[tm], b[tn], acc[tm * 8 + tn], 0, 0, 0);
        }
    }

    const int qr = lane >> 4, c = lane & 15;
    #pragma unroll
    for (int tm = 0; tm < 2; tm++) {
        #pragma unroll
        for (int tn = 0; tn < 4; tn++) {
            f32x4 p = acc[tm * 8 + tn];
            f32x4 q = acc[tm * 8 + tn + 4];
            #pragma unroll
            for (int r = 0; r < 4; r++) {
                int m = w * 32 + tm * 16 + qr * 4 + r;
                out[(size_t)(rb * 128 + m) * 256 + cb * 64 + tn * 16 + c] =
                    p[r] * p[r] + q[r] * q[r];
            }
        }
    }
}

// ---------------- host ------------------------------------------------------
extern "C" void kernel_launch(void* const* d_in, const int* in_sizes, int n_in,
                              void* d_out, int out_size, void* d_ws, size_t ws_size,
                              hipStream_t stream) {
    (void)in_sizes; (void)n_in; (void)out_size;
    const float* x      = (const float*)d_in[0];
    const float* rots1  = (const float*)d_in[1];
    const float* phases = (const float*)d_in[2];
    const float* rots2  = (const float*)d_in[3];
    float* out = (float*)d_out;
    char* ws = (char*)d_ws;

    const size_t MAT = 262144;                 // 256x256 fp32
    int pblk = 64;
    while (pblk > 16 &&
           (size_t)3 * pblk * MAT + 2 * MAT + (size_t)BATCH * 512 > ws_size)
        pblk >>= 1;
    const size_t offA   = 0;
    const size_t offB   = offA + (size_t)2 * pblk * MAT;   // A: 2*pblk mats
    const size_t offABT = offB + (size_t)pblk * MAT;       // B: pblk mats
    const size_t offINV = offABT + MAT;
    const size_t offXBF = offINV + MAT;
    const bool use_xbf = (offXBF + (size_t)BATCH * 512) <= ws_size;

    float*          A    = (float*)(ws + offA);
    float*          B    = (float*)(ws + offB);
    unsigned short* abt  = (unsigned short*)(ws + offABT);
    float*          invn = (float*)(ws + offINV);
    unsigned short* xbf  = (unsigned short*)(ws + offXBF);
    // cos/sin table overlays the B ping-pong buffer: written by k_cs, read by
    // k_blocks, dead by the time combine round 1 overwrites B.
    float2*         cs   = (float2*)(ws + offB);

    k_cs<<<(2 * NROT) / 256, 256, 0, stream>>>(rots1, rots2, cs);
    k_blocks<<<8 * pblk, 64, 0, stream>>>(cs, A, pblk);

    float* srcp = A; float* dstp = B;
    bool first = true;
    for (int half = pblk / 2; half >= 1; half >>= 1) {
        const int xny = (first && use_xbf) ? 64 : 0;
        k_combine<<<dim3(16, 2 * half + xny), 256, 0, stream>>>(srcp, dstp, half,
                                                                pblk, x, xbf);
        float* tmp = srcp; srcp = dstp; dstp = tmp;
        first = false;
    }
    // ABT via K-split partials into the free ping buffer (needs 4 MB;
    // dstp region is >= pblk*MAT = 4 MB even at pblk=16), then reduce.
    k_abt_part<<<dim3(16, 2, 8), 256, 0, stream>>>(srcp, phases, dstp);
    k_abt_red<<<128, 256, 0, stream>>>(dstp, abt);

    if (use_xbf) {
        k_gemm_bf<<<dim3(4, BATCH / 128), 256, 0, stream>>>(xbf, abt, out);
    } else {
        k_norm<<<BATCH / 4, 256, 0, stream>>>(x, invn);
        k_gemm_f32<<<dim3(4, BATCH / 128), 256, 0, stream>>>(x, abt, invn, out);
    }
}

// Round 9
// 261.488 us; speedup vs baseline: 1.0883x; 1.0024x over previous
//
#include <hip/hip_runtime.h>
#include <stdint.h>
#include <math.h>

#define NDIM 256
#define BATCH 65536
#define NROT 32640          // 256*255/2

typedef float  f32x4 __attribute__((ext_vector_type(4)));
typedef short  s16x8 __attribute__((ext_vector_type(8)));
typedef unsigned int u32x4 __attribute__((ext_vector_type(4)));
typedef unsigned int u32x2 __attribute__((ext_vector_type(2)));

// round-to-nearest-even float -> bf16 bits
static __device__ __forceinline__ unsigned short f2bf(float f) {
    unsigned int u = __float_as_uint(f);
    u += 0x7fffu + ((u >> 16) & 1u);
    return (unsigned short)(u >> 16);
}
static __device__ __forceinline__ float bf2f(unsigned short h) {
    return __uint_as_float(((unsigned)h) << 16);
}

// split 4 fp32 -> bf16 hi + bf16 lo (packed).  a ~= hi + lo, |err| ~ 2^-18|a|
static __device__ __forceinline__ void split4(f32x4 v, u32x2* hi, u32x2* lo) {
    unsigned short h[4], l[4];
    #pragma unroll
    for (int i = 0; i < 4; i++) {
        h[i] = f2bf(v[i]);
        l[i] = f2bf(v[i] - bf2f(h[i]));
    }
    *hi = (u32x2){ (unsigned)h[0] | ((unsigned)h[1] << 16),
                   (unsigned)h[2] | ((unsigned)h[3] << 16) };
    *lo = (u32x2){ (unsigned)l[0] | ((unsigned)l[1] << 16),
                   (unsigned)l[2] | ((unsigned)l[3] << 16) };
}
static __device__ __forceinline__ void split8(const float* v, u32x4* hi, u32x4* lo) {
    unsigned short h[8], l[8];
    #pragma unroll
    for (int i = 0; i < 8; i++) {
        h[i] = f2bf(v[i]);
        l[i] = f2bf(v[i] - bf2f(h[i]));
    }
    *hi = (u32x4){ (unsigned)h[0] | ((unsigned)h[1] << 16),
                   (unsigned)h[2] | ((unsigned)h[3] << 16),
                   (unsigned)h[4] | ((unsigned)h[5] << 16),
                   (unsigned)h[6] | ((unsigned)h[7] << 16) };
    *lo = (u32x4){ (unsigned)l[0] | ((unsigned)l[1] << 16),
                   (unsigned)l[2] | ((unsigned)l[3] << 16),
                   (unsigned)l[4] | ((unsigned)l[5] << 16),
                   (unsigned)l[6] | ((unsigned)l[7] << 16) };
}

// nearest 4-aligned sweep boundary to k*(NROT/pblk); shared by k_blocks
// and k_combine (the block-diagonal skip logic depends on agreement).
static __device__ __forceinline__ int sweep_bound(int k, int pblk) {
    int target = k * (NROT / pblk);
    int best = 0, bd = 0x7fffffff;
    for (int i = 0; i <= 256; i += 4) {
        int pre = i * 255 - (i * (i - 1)) / 2;
        int d = pre - target; d = (d < 0) ? -d : d;
        if (d < bd) { bd = d; best = i; }
    }
    return best;
}

// ---------------- kernel 0: angle table (cos,sin) for both rot sets ---------
__global__ __launch_bounds__(256) void k_cs(const float* __restrict__ r1,
                                            const float* __restrict__ r2,
                                            float2* __restrict__ cs) {
    int i = blockIdx.x * 256 + threadIdx.x;          // 0 .. 2*NROT-1
    float th = (i < NROT) ? r1[i] : r2[i - NROT];
    float sv, cv; sincosf(th, &sv, &cv);
    cs[i] = make_float2(cv, sv);
}

// ---------------- kernel 1: blocks + wave-specialized xnorm -----------------
// Wave 0 runs the (latency-bound, ~90% stalled) rotation chain exactly as
// before -- it is the only LDS user and there are no barriers. Waves 1-3
// stream the x -> xbf bf16 normalization (no LDS, no extra WG slots), filling
// wave 0's idle issue slots. This is the intra-WG form of the R1 fusion that
// failed as separate-WG fusion (77 KB LDS inherited -> serialized batches).
__global__ __launch_bounds__(256) void k_blocks(const float2* __restrict__ cs,
                                                float* __restrict__ bmats, int pblk,
                                                const float* __restrict__ xg,
                                                unsigned short* __restrict__ xbf,
                                                int do_xn) {
    __shared__ float colb[264 * 64];
    __shared__ float2 csb[256 * 4];     // single-buffered steady angles
    __shared__ float2 tri[24 * 6];      // all groups' triangle angles

    const int bid = blockIdx.x;
    const int wid = threadIdx.x >> 6;
    const int lane = threadIdx.x & 63;

    if (wid != 0) {                     // ---- xnorm waves (1..3) ----
        if (!do_xn) return;
        const int W  = bid * 3 + (wid - 1);
        const int nW = (int)gridDim.x * 3;
        const int per = (BATCH + nW - 1) / nW;
        int r0 = W * per;
        int rend = r0 + per; if (rend > BATCH) rend = BATCH;
        for (int row = r0; row < rend; row += 2) {
            const bool has2 = (row + 1 < rend);
            f32x4 v0 = *(const f32x4*)&xg[(size_t)row * 256 + lane * 4];
            f32x4 v1 = has2 ? *(const f32x4*)&xg[(size_t)(row + 1) * 256 + lane * 4]
                            : v0;
            float s0 = v0[0] * v0[0] + v0[1] * v0[1] + v0[2] * v0[2] + v0[3] * v0[3];
            float s1 = v1[0] * v1[0] + v1[1] * v1[1] + v1[2] * v1[2] + v1[3] * v1[3];
            #pragma unroll
            for (int off = 32; off; off >>= 1) {
                s0 += __shfl_xor(s0, off, 64);
                s1 += __shfl_xor(s1, off, 64);
            }
            float sc0 = 1.0f / sqrtf(s0), sc1 = 1.0f / sqrtf(s1);
            {
                unsigned short h0 = f2bf(v0[0] * sc0), h1 = f2bf(v0[1] * sc0);
                unsigned short h2 = f2bf(v0[2] * sc0), h3 = f2bf(v0[3] * sc0);
                u32x2 pk = { (unsigned)h0 | ((unsigned)h1 << 16),
                             (unsigned)h2 | ((unsigned)h3 << 16) };
                *(u32x2*)&xbf[(size_t)row * 256 + lane * 4] = pk;
            }
            if (has2) {
                unsigned short h0 = f2bf(v1[0] * sc1), h1 = f2bf(v1[1] * sc1);
                unsigned short h2 = f2bf(v1[2] * sc1), h3 = f2bf(v1[3] * sc1);
                u32x2 pk = { (unsigned)h0 | ((unsigned)h1 << 16),
                             (unsigned)h2 | ((unsigned)h3 << 16) };
                *(u32x2*)&xbf[(size_t)(row + 1) * 256 + lane * 4] = pk;
            }
        }
        return;
    }

    // ---- wave 0: rotation chain (unchanged from R8) ----
    const int t = lane;                 // column within chunk
    const int chunk = bid & 3;          // 0..3 (64 cols each)
    const int b = (bid >> 2) % pblk;    // 0..pblk-1
    const int set = (bid >> 2) / pblk;  // 0 = rots1, 1 = rots2
    const int col0 = chunk * 64;
    const float2* cst = cs + (size_t)set * NROT;

    const int s0 = sweep_bound(b, pblk);
    const int s1 = sweep_bound(b + 1, pblk);
    const int ngroups = (s1 - s0) >> 2;

    // zero colb (incl. pad rows 256..263), set identity diagonal
    {
        const f32x4 z = {0.f, 0.f, 0.f, 0.f};
        #pragma unroll 11
        for (int q = 0; q < 66; q++)
            *(f32x4*)&colb[(q * 64 + t) * 4] = z;
        colb[(col0 + t) * 64 + t] = 1.0f;
    }

    // stage all triangle angles (6 per group) into LDS
    for (int k = t; k < ngroups * 6; k += 64) {
        int g = k / 6, q = k - g * 6;
        int a  = (q < 3) ? 0 : ((q < 5) ? 1 : 2);
        int bb = (q < 3) ? (q + 1) : ((q < 5) ? (q - 1) : 3);
        int m0 = s0 + g * 4;
        int m = m0 + a;
        int base = m * 255 - (m * (m - 1)) / 2;
        tri[k] = cst[base - m - 1 + m0 + bb];
    }
    // single-wave LDS user: DS pipe is in-order per wave, no barrier needed

    float2 gv[16];                      // in-flight staging registers
    {
        const int m0g = s0;
        int offg[4];
        #pragma unroll
        for (int a = 0; a < 4; a++) {
            int m = m0g + a;
            offg[a] = m * 255 - (m * (m - 1)) / 2 - m - 1;
        }
        #pragma unroll
        for (int it = 0; it < 16; it++) {
            int k = t + it * 64;
            int jj = k >> 2, a = k & 3;
            int j = m0g + 4 + jj;
            gv[it] = (j < 256) ? cst[offg[a] + j] : make_float2(1.f, 0.f);
        }
        #pragma unroll
        for (int it = 0; it < 16; it++)
            csb[t + it * 64] = gv[it];
    }

    for (int g = 0; g < ngroups; g++) {
        const int m0 = s0 + g * 4;
        const int n_j = 252 - m0;
        const int n_p = (n_j > 0) ? ((n_j + 7) & ~7) : 0;
        const float* csbuf = (const float*)&csb[0];

        // issue NEXT group's staging loads (latency hides under this j-loop)
        const bool have_next = (g + 1 < ngroups);
        if (have_next) {
            const int m0g = m0 + 4;
            int offg[4];
            #pragma unroll
            for (int a = 0; a < 4; a++) {
                int m = m0g + a;
                offg[a] = m * 255 - (m * (m - 1)) / 2 - m - 1;
            }
            #pragma unroll
            for (int it = 0; it < 16; it++) {
                int k = t + it * 64;
                int jj = k >> 2, a = k & 3;
                int j = m0g + 4 + jj;
                gv[it] = (j < 256) ? cst[offg[a] + j] : make_float2(1.f, 0.f);
            }
        }

        float u0 = colb[(m0 + 0) * 64 + t];
        float u1 = colb[(m0 + 1) * 64 + t];
        float u2 = colb[(m0 + 2) * 64 + t];
        float u3 = colb[(m0 + 3) * 64 + t];

        {
            float2 cv; float nr;
            cv = tri[g * 6 + 0]; nr = cv.y * u0 + cv.x * u1; u0 = cv.x * u0 - cv.y * u1; u1 = nr;
            cv = tri[g * 6 + 1]; nr = cv.y * u0 + cv.x * u2; u0 = cv.x * u0 - cv.y * u2; u2 = nr;
            cv = tri[g * 6 + 2]; nr = cv.y * u0 + cv.x * u3; u0 = cv.x * u0 - cv.y * u3; u3 = nr;
            cv = tri[g * 6 + 3]; nr = cv.y * u1 + cv.x * u2; u1 = cv.x * u1 - cv.y * u2; u2 = nr;
            cv = tri[g * 6 + 4]; nr = cv.y * u1 + cv.x * u3; u1 = cv.x * u1 - cv.y * u3; u3 = nr;
            cv = tri[g * 6 + 5]; nr = cv.y * u2 + cv.x * u3; u2 = cv.x * u2 - cv.y * u3; u3 = nr;
        }

        if (n_p > 0) {
            float rbuf[8];
            f32x4 abuf[8][2];
            #pragma unroll
            for (int p = 0; p < 8; p++) {
                rbuf[p] = colb[(m0 + 4 + p) * 64 + t];
                abuf[p][0] = *(const f32x4*)&csbuf[p * 8 + 0];
                abuf[p][1] = *(const f32x4*)&csbuf[p * 8 + 4];
            }
            for (int c = 0; c < n_p; c += 8) {
                #pragma unroll
                for (int p = 0; p < 8; p++) {
                    const int j = m0 + 4 + c + p;
                    float r = rbuf[p];
                    f32x4 A01 = abuf[p][0], A23 = abuf[p][1];
                    int jn = j + 8; jn = (jn < 263) ? jn : 263;
                    int cn = c + p + 8; cn = (cn < n_p) ? cn : (n_p - 1);
                    rbuf[p] = colb[jn * 64 + t];
                    abuf[p][0] = *(const f32x4*)&csbuf[cn * 8 + 0];
                    abuf[p][1] = *(const f32x4*)&csbuf[cn * 8 + 4];
                    float nr;
                    nr = A01[1] * u0 + A01[0] * r; u0 = A01[0] * u0 - A01[1] * r; r = nr;
                    nr = A01[3] * u1 + A01[2] * r; u1 = A01[2] * u1 - A01[3] * r; r = nr;
                    nr = A23[1] * u2 + A23[0] * r; u2 = A23[0] * u2 - A23[1] * r; r = nr;
                    nr = A23[3] * u3 + A23[2] * r; u3 = A23[2] * u3 - A23[3] * r; r = nr;
                    colb[j * 64 + t] = r;
                }
            }
        }
        colb[(m0 + 0) * 64 + t] = u0;
        colb[(m0 + 1) * 64 + t] = u1;
        colb[(m0 + 2) * 64 + t] = u2;
        colb[(m0 + 3) * 64 + t] = u3;

        // commit next group's staged angles (after this group's csb reads)
        if (have_next) {
            #pragma unroll
            for (int it = 0; it < 16; it++)
                csb[t + it * 64] = gv[it];
        }
    }

    float* outm = bmats + (size_t)(set * pblk + b) * 65536;
    for (int r = 0; r < 256; r++)
        outm[(size_t)r * 256 + col0 + t] = colb[r * 64 + t];
}

// ---------------- pipelined 64x64 matmul tile helpers -----------------------
// Single-buffered LDS (20 KB total -> 8 WGs/CU); 2-deep register prefetch.
#define TB 2560   // 64*40 shorts per buffer

// B k-slot XOR swizzle: physical slot = s ^ ((row>>3)&3).
static __device__ __forceinline__ int bslot(int row, int s) {
    return row * 40 + ((s ^ ((row >> 3) & 3)) << 3);
}

static __device__ __forceinline__ void tile_issueA(const float* __restrict__ Am,
                                                   int tr, int kb, int tid,
                                                   f32x4 va[2]) {
    #pragma unroll
    for (int it = 0; it < 2; it++) {
        int flat = tid + it * 256;
        int r = flat >> 3, c4 = flat & 7;
        va[it] = *(const f32x4*)&Am[(size_t)(tr * 64 + r) * 256 + kb * 32 + c4 * 4];
    }
}
static __device__ __forceinline__ void tile_issueB(const float* __restrict__ Bm,
                                                   int tc, int kb, int bn, int bkq,
                                                   float vb[8]) {
    #pragma unroll
    for (int i = 0; i < 8; i++)
        vb[i] = Bm[(size_t)(kb * 32 + bkq * 8 + i) * 256 + tc * 64 + bn];
}
static __device__ __forceinline__ void tile_commit(unsigned short* __restrict__ Ahi,
                                                   unsigned short* __restrict__ Alo,
                                                   unsigned short* __restrict__ Bhi,
                                                   unsigned short* __restrict__ Blo,
                                                   int tid, int bn, int bkq,
                                                   const f32x4 va[2], const float vb[8]) {
    #pragma unroll
    for (int it = 0; it < 2; it++) {
        int flat = tid + it * 256;
        int r = flat >> 3, c4 = flat & 7;
        u32x2 hi, lo; split4(va[it], &hi, &lo);
        *(u32x2*)&Ahi[r * 40 + c4 * 4] = hi;
        *(u32x2*)&Alo[r * 40 + c4 * 4] = lo;
    }
    u32x4 hi8, lo8; split8(vb, &hi8, &lo8);
    *(u32x4*)&Bhi[bslot(bn, bkq)] = hi8;
    *(u32x4*)&Blo[bslot(bn, bkq)] = lo8;
}
static __device__ __forceinline__ void tile_mfma(const unsigned short* __restrict__ Ahi,
                                                 const unsigned short* __restrict__ Alo,
                                                 const unsigned short* __restrict__ Bhi,
                                                 const unsigned short* __restrict__ Blo,
                                                 int mh, int nh, int l15, int lq,
                                                 f32x4 acc[2][2]) {
    s16x8 ah[2], al[2], bh[2], bl[2];
    #pragma unroll
    for (int tm = 0; tm < 2; tm++) {
        ah[tm] = *(const s16x8*)&Ahi[(mh + tm * 16 + l15) * 40 + lq * 8];
        al[tm] = *(const s16x8*)&Alo[(mh + tm * 16 + l15) * 40 + lq * 8];
    }
    #pragma unroll
    for (int tn = 0; tn < 2; tn++) {
        bh[tn] = *(const s16x8*)&Bhi[bslot(nh + tn * 16 + l15, lq)];
        bl[tn] = *(const s16x8*)&Blo[bslot(nh + tn * 16 + l15, lq)];
    }
    #pragma unroll
    for (int tm = 0; tm < 2; tm++)
        #pragma unroll
        for (int tn = 0; tn < 2; tn++) {
            acc[tm][tn] = __builtin_amdgcn_mfma_f32_16x16x32_bf16(ah[tm], bh[tn], acc[tm][tn], 0, 0, 0);
            acc[tm][tn] = __builtin_amdgcn_mfma_f32_16x16x32_bf16(ah[tm], bl[tn], acc[tm][tn], 0, 0, 0);
            acc[tm][tn] = __builtin_amdgcn_mfma_f32_16x16x32_bf16(al[tm], bh[tn], acc[tm][tn], 0, 0, 0);
        }
}

// one 64x64 combine tile: dst[p] = src[2p+1] @ src[2p].
// Pipeline: commit(kb); sync; issue(kb+2); mfma(kb); sync.
static __device__ void combine_tile(const float* __restrict__ src,
                                    float* __restrict__ dst,
                                    int half, int pblk, int bx, int by, int tid,
                                    unsigned short* Ahi, unsigned short* Alo,
                                    unsigned short* Bhi, unsigned short* Blo) {
    const int set = by / half, pidx = by % half;
    const int stride = pblk / (2 * half);
    const int s0A = sweep_bound((2 * pidx + 1) * stride, pblk);
    const float* Am = src + (size_t)(set * 2 * half + 2 * pidx + 1) * 65536;
    const float* Bm = src + (size_t)(set * 2 * half + 2 * pidx) * 65536;
    float* Dm = dst + (size_t)(set * half + pidx) * 65536;
    const int tr = bx >> 2, tc = bx & 3;

    if (tr * 64 + 64 <= s0A) {                 // pure copy tile: D = B
        #pragma unroll
        for (int it = 0; it < 4; it++) {
            int flat = tid + it * 256;
            int r = flat >> 4, c4 = flat & 15;
            size_t idx = (size_t)(tr * 64 + r) * 256 + tc * 64 + c4 * 4;
            *(f32x4*)&Dm[idx] = *(const f32x4*)&Bm[idx];
        }
        return;
    }
    const int kb0 = (tr * 64 >= s0A) ? (s0A >> 5) : 0;

    const int lane = tid & 63, w = tid >> 6;
    const int mh = (w >> 1) * 32, nh = (w & 1) * 32;
    const int l15 = lane & 15, lq = lane >> 4;
    const int bn = tid & 63, bkq = tid >> 6;

    f32x4 acc[2][2];
    #pragma unroll
    for (int i = 0; i < 2; i++)
        #pragma unroll
        for (int j = 0; j < 2; j++) acc[i][j] = (f32x4){0.f, 0.f, 0.f, 0.f};

    f32x4 vaE[2], vaO[2]; float vbE[8], vbO[8];
    tile_issueA(Am, tr, kb0, tid, vaE);
    tile_issueB(Bm, tc, kb0, bn, bkq, vbE);
    if (kb0 + 1 < 8) {
        tile_issueA(Am, tr, kb0 + 1, tid, vaO);
        tile_issueB(Bm, tc, kb0 + 1, bn, bkq, vbO);
    }

    for (int kb = kb0; kb < 8; kb++) {
        const int cur = (kb - kb0) & 1;
        if (cur == 0) {
            tile_commit(Ahi, Alo, Bhi, Blo, tid, bn, bkq, vaE, vbE);
            __syncthreads();
            if (kb + 2 < 8) {           // reuse freed E regs
                tile_issueA(Am, tr, kb + 2, tid, vaE);
                tile_issueB(Bm, tc, kb + 2, bn, bkq, vbE);
            }
        } else {
            tile_commit(Ahi, Alo, Bhi, Blo, tid, bn, bkq, vaO, vbO);
            __syncthreads();
            if (kb + 2 < 8) {
                tile_issueA(Am, tr, kb + 2, tid, vaO);
                tile_issueB(Bm, tc, kb + 2, bn, bkq, vbO);
            }
        }
        tile_mfma(Ahi, Alo, Bhi, Blo, mh, nh, l15, lq, acc);
        __syncthreads();                // protect LDS reuse by next commit
    }
    #pragma unroll
    for (int tm = 0; tm < 2; tm++)
        #pragma unroll
        for (int tn = 0; tn < 2; tn++)
            #pragma unroll
            for (int r = 0; r < 4; r++)
                Dm[(size_t)(tr * 64 + mh + tm * 16 + lq * 4 + r) * 256
                   + tc * 64 + nh + tn * 16 + l15] = acc[tm][tn][r];
}

// ---------------- kernel wrappers -------------------------------------------
__global__ __launch_bounds__(256) void k_combine(const float* __restrict__ src,
                                                 float* __restrict__ dst,
                                                 int half, int pblk) {
    __shared__ unsigned short Ahi[TB], Alo[TB], Bhi[TB], Blo[TB];
    combine_tile(src, dst, half, pblk, blockIdx.x, blockIdx.y, threadIdx.x,
                 Ahi, Alo, Bhi, Blo);
}

// ---------------- kernel 3a: K-split ABT partials ---------------------------
// ABT = M2 @ diag(cos|sin(phases)) @ M1, K-split 8 ways. grid (16, 2, 8) =
// 256 WGs; each WG does ONE k-phase and writes an fp32 partial.
__global__ __launch_bounds__(256) void k_abt_part(const float* __restrict__ mats,
                                                  const float* __restrict__ phases,
                                                  float* __restrict__ part) {
    __shared__ unsigned short Ahi[TB], Alo[TB], Bhi[TB], Blo[TB];
    const float* Am = mats + 65536;    // M2
    const float* Bm = mats;            // M1
    const int tid = threadIdx.x;
    const int bx = blockIdx.x;         // 0..15 output tile
    const int v  = blockIdx.y;         // 0: cos, 1: sin
    const int kb = blockIdx.z;         // 0..7 K-chunk (32 wide)
    const int tr = bx >> 2, tc = bx & 3;

    const int lane = tid & 63, w = tid >> 6;
    const int mh = (w >> 1) * 32, nh = (w & 1) * 32;
    const int l15 = lane & 15, lq = lane >> 4;
    const int bn = tid & 63, bkq = tid >> 6;

    f32x4 va[2]; float vb[8];
    tile_issueA(Am, tr, kb, tid, va);
    #pragma unroll
    for (int i = 0; i < 8; i++) {
        int kg = kb * 32 + bkq * 8 + i;            // wave-uniform k index
        float ph = phases[kg];
        float sc = v ? sinf(ph) : cosf(ph);
        vb[i] = Bm[(size_t)kg * 256 + tc * 64 + bn] * sc;
    }

    f32x4 acc[2][2];
    #pragma unroll
    for (int i = 0; i < 2; i++)
        #pragma unroll
        for (int j = 0; j < 2; j++) acc[i][j] = (f32x4){0.f, 0.f, 0.f, 0.f};

    tile_commit(Ahi, Alo, Bhi, Blo, tid, bn, bkq, va, vb);
    __syncthreads();
    tile_mfma(Ahi, Alo, Bhi, Blo, mh, nh, l15, lq, acc);

    float* pp = part + (size_t)(kb * 2 + v) * 65536;   // [kz][v][256][256]
    #pragma unroll
    for (int tm = 0; tm < 2; tm++)
        #pragma unroll
        for (int tn = 0; tn < 2; tn++)
            #pragma unroll
            for (int r = 0; r < 4; r++)
                pp[(size_t)(tr * 64 + mh + tm * 16 + lq * 4 + r) * 256
                   + tc * 64 + nh + tn * 16 + l15] = acc[tm][tn][r];
}

// ---------------- kernel 3b: reduce 8 partials -> bf16 abt ------------------
__global__ __launch_bounds__(256) void k_abt_red(const float* __restrict__ part,
                                                 unsigned short* __restrict__ abt) {
    const int e = (blockIdx.x * 256 + threadIdx.x) * 4;   // over [2][65536]
    f32x4 s = {0.f, 0.f, 0.f, 0.f};
    #pragma unroll
    for (int kz = 0; kz < 8; kz++)
        s += *(const f32x4*)&part[(size_t)kz * 131072 + e];
    unsigned short h0 = f2bf(s[0]), h1 = f2bf(s[1]);
    unsigned short h2 = f2bf(s[2]), h3 = f2bf(s[3]);
    u32x2 pk = { (unsigned)h0 | ((unsigned)h1 << 16),
                 (unsigned)h2 | ((unsigned)h3 << 16) };
    *(u32x2*)&abt[e] = pk;
}

// ---------------- kernel 4b: per-row 1/||x|| (fallback path) ----------------
__global__ __launch_bounds__(256) void k_norm(const float* __restrict__ x,
                                              float* __restrict__ invn) {
    const int row = blockIdx.x * 4 + (threadIdx.x >> 6);
    const int lane = threadIdx.x & 63;
    f32x4 v = *(const f32x4*)&x[(size_t)row * 256 + lane * 4];
    float s = v[0] * v[0] + v[1] * v[1] + v[2] * v[2] + v[3] * v[3];
    for (int off = 32; off; off >>= 1) s += __shfl_xor(s, off, 64);
    if (lane == 0) invn[row] = 1.0f / sqrtf(s);
}

// ---------------- kernel 5a: GEMM + |.|^2 from pre-converted bf16 x ---------
// XCD swizzle: remap l=(y*4+x) -> L=(l&7)*256+(l>>3): each XCD gets 64
// contiguous rb x all 4 cb -> x-tile fetched once per XCD (4 MB = L2-sized).
#define BKP 136   // padded LDS k-stride (bf16 elems)
__global__ __launch_bounds__(256) void k_gemm_bf(const unsigned short* __restrict__ xbf,
                                                 const unsigned short* __restrict__ abt,
                                                 float* __restrict__ out) {
    __shared__ unsigned short As[128 * BKP];
    __shared__ unsigned short Bs[128 * BKP];
    const int tid = threadIdx.x;
    const int l  = blockIdx.y * 4 + blockIdx.x;
    const int L  = (l & 7) * 256 + (l >> 3);
    const int cb = L & 3;               // 0..3  (64 out-cols each)
    const int rb = L >> 2;              // 0..511
    const int lane = tid & 63, w = tid >> 6;

    f32x4 acc[16];
    #pragma unroll
    for (int i = 0; i < 16; i++) acc[i] = (f32x4){0.f, 0.f, 0.f, 0.f};

    int rA[8], cA[8], grB[8];
    #pragma unroll
    for (int it = 0; it < 8; it++) {
        int flat = tid + it * 256;
        rA[it] = flat >> 4; cA[it] = flat & 15;
        int r = rA[it];
        grB[it] = (r < 64) ? (cb * 64 + r) : (256 + cb * 64 + (r - 64));
    }

    u32x4 pa[8], pb[8];
    #pragma unroll
    for (int it = 0; it < 8; it++) {
        pa[it] = *(const u32x4*)&xbf[(size_t)(rb * 128 + rA[it]) * 256 + cA[it] * 8];
        pb[it] = *(const u32x4*)&abt[(size_t)grB[it] * 256 + cA[it] * 8];
    }
    #pragma unroll
    for (int it = 0; it < 8; it++) {
        *(u32x4*)&As[rA[it] * BKP + cA[it] * 8] = pa[it];
        *(u32x4*)&Bs[rA[it] * BKP + cA[it] * 8] = pb[it];
    }
    __syncthreads();
    #pragma unroll
    for (int it = 0; it < 8; it++) {
        pa[it] = *(const u32x4*)&xbf[(size_t)(rb * 128 + rA[it]) * 256 + 128 + cA[it] * 8];
        pb[it] = *(const u32x4*)&abt[(size_t)grB[it] * 256 + 128 + cA[it] * 8];
    }

    auto compute = [&]() {
        #pragma unroll
        for (int ks = 0; ks < 4; ks++) {
            const int k0 = ks * 32 + (lane >> 4) * 8;
            s16x8 a[2], b[8];
            #pragma unroll
            for (int tm = 0; tm < 2; tm++)
                a[tm] = *(const s16x8*)&As[(w * 32 + tm * 16 + (lane & 15)) * BKP + k0];
            #pragma unroll
            for (int tn = 0; tn < 8; tn++)
                b[tn] = *(const s16x8*)&Bs[(tn * 16 + (lane & 15)) * BKP + k0];
            #pragma unroll
            for (int tm = 0; tm < 2; tm++)
                #pragma unroll
                for (int tn = 0; tn < 8; tn++)
                    acc[tm * 8 + tn] = __builtin_amdgcn_mfma_f32_16x16x32_bf16(
                        a[tm], b[tn], acc[tm * 8 + tn], 0, 0, 0);
        }
    };
    compute();                 // kb=0
    __syncthreads();
    #pragma unroll
    for (int it = 0; it < 8; it++) {
        *(u32x4*)&As[rA[it] * BKP + cA[it] * 8] = pa[it];
        *(u32x4*)&Bs[rA[it] * BKP + cA[it] * 8] = pb[it];
    }
    __syncthreads();
    compute();                 // kb=1

    const int qr = lane >> 4, c = lane & 15;
    #pragma unroll
    for (int tm = 0; tm < 2; tm++) {
        #pragma unroll
        for (int tn = 0; tn < 4; tn++) {
            f32x4 p = acc[tm * 8 + tn];
            f32x4 q = acc[tm * 8 + tn + 4];
            #pragma unroll
            for (int r = 0; r < 4; r++) {
                int m = w * 32 + tm * 16 + qr * 4 + r;
                out[(size_t)(rb * 128 + m) * 256 + cb * 64 + tn * 16 + c] =
                    p[r] * p[r] + q[r] * q[r];
            }
        }
    }
}

// ---------------- kernel 5b: GEMM + |.|^2 from fp32 x (fallback) ------------
__global__ __launch_bounds__(256) void k_gemm_f32(const float* __restrict__ x,
                                                  const unsigned short* __restrict__ abt,
                                                  const float* __restrict__ invn,
                                                  float* __restrict__ out) {
    __shared__ unsigned short As[128 * BKP];
    __shared__ unsigned short Bs[128 * BKP];
    const int tid = threadIdx.x;
    const int l  = blockIdx.y * 4 + blockIdx.x;
    const int L  = (l & 7) * 256 + (l >> 3);
    const int cb = L & 3;
    const int rb = L >> 2;
    const int lane = tid & 63, w = tid >> 6;

    f32x4 acc[16];
    #pragma unroll
    for (int i = 0; i < 16; i++) acc[i] = (f32x4){0.f, 0.f, 0.f, 0.f};

    for (int kb = 0; kb < 2; kb++) {
        __syncthreads();
        #pragma unroll
        for (int it = 0; it < 16; it++) {
            int flat = tid + it * 256;
            int r = flat >> 5, c4 = flat & 31;
            f32x4 v = *(const f32x4*)&x[(size_t)(rb * 128 + r) * 256 + kb * 128 + c4 * 4];
            float sc = invn[rb * 128 + r];
            v[0] *= sc; v[1] *= sc; v[2] *= sc; v[3] *= sc;
            unsigned short h0 = f2bf(v[0]), h1 = f2bf(v[1]);
            unsigned short h2 = f2bf(v[2]), h3 = f2bf(v[3]);
            u32x2 pk = { (unsigned)h0 | ((unsigned)h1 << 16),
                         (unsigned)h2 | ((unsigned)h3 << 16) };
            *(u32x2*)&As[r * BKP + c4 * 4] = pk;
        }
        #pragma unroll
        for (int it = 0; it < 8; it++) {
            int flat = tid + it * 256;
            int r = flat >> 4, c8 = flat & 15;
            int gr = (r < 64) ? (cb * 64 + r) : (256 + cb * 64 + (r - 64));
            u32x4 vv = *(const u32x4*)&abt[(size_t)gr * 256 + kb * 128 + c8 * 8];
            *(u32x4*)&Bs[r * BKP + c8 * 8] = vv;
        }
        __syncthreads();
        #pragma unroll
        for (int ks = 0; ks < 4; ks++) {
            const int k0 = ks * 32 + (lane >> 4) * 8;
            s16x8 a[2], b[8];
            #pragma unroll
            for (int tm = 0; tm < 2; tm++)
                a[tm] = *(const s16x8*)&As[(w * 32 + tm * 16 + (lane & 15)) * BKP + k0];
            #pragma unroll
            for (int tn = 0; tn < 8; tn++)
                b[tn] = *(const s16x8*)&Bs[(tn * 16 + (lane & 15)) * BKP + k0];
            #pragma unroll
            for (int tm = 0; tm < 2; tm++)
                #pragma unroll
                for (int tn = 0; tn < 8; tn++)
                    acc[tm * 8 + tn] = __builtin_amdgcn_mfma_f32_16x16x32_bf16(
                        a[tm], b[tn], acc[tm * 8 + tn], 0, 0, 0);
        }
    }

    const int qr = lane >> 4, c = lane & 15;
    #pragma unroll
    for (int tm = 0; tm < 2; tm++) {
        #pragma unroll
        for (int tn = 0; tn < 4; tn++) {
            f32x4 p = acc[tm * 8 + tn];
            f32x4 q = acc[tm * 8 + tn + 4];
            #pragma unroll
            for (int r = 0; r < 4; r++) {
                int m = w * 32 + tm * 16 + qr * 4 + r;
                out[(size_t)(rb * 128 + m) * 256 + cb * 64 + tn * 16 + c] =
                    p[r] * p[r] + q[r] * q[r];
            }
        }
    }
}

// ---------------- host ------------------------------------------------------
extern "C" void kernel_launch(void* const* d_in, const int* in_sizes, int n_in,
                              void* d_out, int out_size, void* d_ws, size_t ws_size,
                              hipStream_t stream) {
    (void)in_sizes; (void)n_in; (void)out_size;
    const float* x      = (const float*)d_in[0];
    const float* rots1  = (const float*)d_in[1];
    const float* phases = (const float*)d_in[2];
    const float* rots2  = (const float*)d_in[3];
    float* out = (float*)d_out;
    char* ws = (char*)d_ws;

    const size_t MAT = 262144;                 // 256x256 fp32
    int pblk = 64;
    while (pblk > 16 &&
           (size_t)3 * pblk * MAT + 2 * MAT + (size_t)BATCH * 512 > ws_size)
        pblk >>= 1;
    const size_t offA   = 0;
    const size_t offB   = offA + (size_t)2 * pblk * MAT;   // A: 2*pblk mats
    const size_t offABT = offB + (size_t)pblk * MAT;       // B: pblk mats
    const size_t offINV = offABT + MAT;
    const size_t offXBF = offINV + MAT;
    const bool use_xbf = (offXBF + (size_t)BATCH * 512) <= ws_size;

    float*          A    = (float*)(ws + offA);
    float*          B    = (float*)(ws + offB);
    unsigned short* abt  = (unsigned short*)(ws + offABT);
    float*          invn = (float*)(ws + offINV);
    unsigned short* xbf  = (unsigned short*)(ws + offXBF);
    // cos/sin table overlays the B ping-pong buffer: written by k_cs, read by
    // k_blocks, dead by the time combine round 1 overwrites B.
    float2*         cs   = (float2*)(ws + offB);

    k_cs<<<(2 * NROT) / 256, 256, 0, stream>>>(rots1, rots2, cs);
    // wave-specialized: wave 0 rotation chain, waves 1-3 stream x -> xbf
    k_blocks<<<8 * pblk, 256, 0, stream>>>(cs, A, pblk, x, xbf, use_xbf ? 1 : 0);

    float* srcp = A; float* dstp = B;
    for (int half = pblk / 2; half >= 1; half >>= 1) {
        k_combine<<<dim3(16, 2 * half), 256, 0, stream>>>(srcp, dstp, half, pblk);
        float* tmp = srcp; srcp = dstp; dstp = tmp;
    }
    // ABT via K-split partials into the free ping buffer (needs 4 MB), reduce.
    k_abt_part<<<dim3(16, 2, 8), 256, 0, stream>>>(srcp, phases, dstp);
    k_abt_red<<<128, 256, 0, stream>>>(dstp, abt);

    if (use_xbf) {
        k_gemm_bf<<<dim3(4, BATCH / 128), 256, 0, stream>>>(xbf, abt, out);
    } else {
        k_norm<<<BATCH / 4, 256, 0, stream>>>(x, invn);
        k_gemm_f32<<<dim3(4, BATCH / 128), 256, 0, stream>>>(x, abt, invn, out);
    }
}